// Round 1
// baseline (1050.592 us; speedup 1.0000x reference)
//
#include <hip/hip_runtime.h>
#include <hip/hip_bf16.h>

#define DEV static __device__ __forceinline__

constexpr int T_ = 2048, DIM_ = 2048, H_ = 16, KVH = 4, D_ = 128;
constexpr int LL = 32, SS = 16, LP_ = 64, TOPK_ = 16, WIN_ = 512;
constexpr int CMP_HID_ = 256, GATE_HID_ = 512;
constexpr int TC_ = 127, NS_ = 32;
constexpr int QKV_N = (H_ + 2 * KVH) * D_;          // 3072
constexpr float SCALE_ = 0.08838834764831845f;       // D^-0.5

typedef __attribute__((ext_vector_type(8))) short short8;
typedef __attribute__((ext_vector_type(4))) float f32x4;

DEV unsigned short f2b(float x) {
    return __builtin_bit_cast(unsigned short, __float2bfloat16(x));
}
DEV float gelu_f(float x) { return 0.5f * x * (1.f + erff(x * 0.70710678118654752f)); }

// ---------------------------------------------------------------------------
// Generic C = A @ W^T + bias  (A:[M,K] f32, W:[N,K] f32), bf16 MFMA inside.
// ACT: 0 = none, 1 = exact gelu.  Writes f32 (Cf) and/or bf16 (Cb).
// N, K multiples of 64/32; M arbitrary (guarded).
// ---------------------------------------------------------------------------
template <int ACT>
__global__ __launch_bounds__(256) void gemm_bt(const float* __restrict__ A,
                                               const float* __restrict__ W,
                                               const float* __restrict__ bias,
                                               float* __restrict__ Cf,
                                               unsigned short* __restrict__ Cb,
                                               int M, int N, int K) {
    __shared__ __align__(16) unsigned short As[64][48];
    __shared__ __align__(16) unsigned short Ws[64][48];
    const int tid = threadIdx.x;
    const int w = tid >> 6, l = tid & 63;
    const int m0 = blockIdx.y * 64, n0 = blockIdx.x * 64;
    const int srow = tid >> 2, scg = (tid & 3) * 8;
    f32x4 acc[4] = {};
    for (int k0 = 0; k0 < K; k0 += 32) {
        {
            const int gr = m0 + srow;
            float v[8];
            if (gr < M) {
                const float* p = A + (size_t)gr * K + k0 + scg;
#pragma unroll
                for (int i = 0; i < 8; i++) v[i] = p[i];
            } else {
#pragma unroll
                for (int i = 0; i < 8; i++) v[i] = 0.f;
            }
#pragma unroll
            for (int i = 0; i < 8; i++) As[srow][scg + i] = f2b(v[i]);
            const float* pw = W + (size_t)(n0 + srow) * K + k0 + scg;
#pragma unroll
            for (int i = 0; i < 8; i++) Ws[srow][scg + i] = f2b(pw[i]);
        }
        __syncthreads();
        short8 af = *(const short8*)&As[w * 16 + (l & 15)][(l >> 4) * 8];
#pragma unroll
        for (int j = 0; j < 4; j++) {
            short8 bf = *(const short8*)&Ws[j * 16 + (l & 15)][(l >> 4) * 8];
            acc[j] = __builtin_amdgcn_mfma_f32_16x16x32_bf16(af, bf, acc[j], 0, 0, 0);
        }
        __syncthreads();
    }
    const int lc = l & 15, lg4 = (l >> 4) * 4;
#pragma unroll
    for (int j = 0; j < 4; j++) {
        const int gc = n0 + j * 16 + lc;
        const float bv = bias[gc];
#pragma unroll
        for (int r = 0; r < 4; r++) {
            const int gr = m0 + w * 16 + lg4 + r;
            if (gr < M) {
                float v = acc[j][r] + bv;
                if (ACT == 1) v = gelu_f(v);
                const size_t idx = (size_t)gr * N + gc;
                if (Cf) Cf[idx] = v;
                if (Cb) Cb[idx] = f2b(v);
            }
        }
    }
}

// ---------------------------------------------------------------------------
// Build compression input matrices: blk[c*KV+kv][l*D+d] = z[c*S+l, kv, d] + cmp_pos[l,d]
// ---------------------------------------------------------------------------
__global__ __launch_bounds__(256) void blk_build(const float* __restrict__ qkv,
                                                 const float* __restrict__ cmp_pos,
                                                 float* __restrict__ blkk,
                                                 float* __restrict__ blkv) {
    const int b = blockIdx.x;                 // 0 .. 2*TC*KV-1
    const int which = (b >= TC_ * KVH) ? 1 : 0;
    const int m = which ? b - TC_ * KVH : b;
    const int c = m / KVH, kv = m % KVH;
    const int col0 = H_ * D_ + which * KVH * D_ + kv * D_;
    float* dst = (which ? blkv : blkk) + (size_t)m * (LL * D_);
    for (int i = threadIdx.x; i < LL * D_; i += 256) {
        const int lrow = i >> 7, d = i & 127;
        dst[i] = qkv[(size_t)(c * SS + lrow) * QKV_N + col0 + d] + cmp_pos[i];
    }
}

// ---------------------------------------------------------------------------
// gate = sigmoid(hg @ W_g2^T + b_g2)
// ---------------------------------------------------------------------------
__global__ void gate2_k(const float* __restrict__ hg, const float* __restrict__ Wg2,
                        const float* __restrict__ bg2, float* __restrict__ gate) {
    const int idx = blockIdx.x * blockDim.x + threadIdx.x;
    if (idx >= T_ * 3) return;
    const int t = idx / 3, i = idx % 3;
    const float* h = hg + (size_t)t * GATE_HID_;
    const float* w = Wg2 + (size_t)i * GATE_HID_;
    float s = bg2[i];
    for (int j = 0; j < GATE_HID_; j++) s += h[j] * w[j];
    gate[idx] = 1.f / (1.f + expf(-s));
}

// ---------------------------------------------------------------------------
// CMP attention (f32), block-score aggregation, top-k block selection -> bitmask.
// Writes obuf = g0 * o_cmp (initializes the whole o buffer).
// One block per query t.
// ---------------------------------------------------------------------------
__global__ __launch_bounds__(256) void cmp_attn(const float* __restrict__ qkv,
                                                const float* __restrict__ kcmp,
                                                const float* __restrict__ vcmp,
                                                const float* __restrict__ gate,
                                                float* __restrict__ obuf,
                                                unsigned int* __restrict__ amask) {
    const int t = blockIdx.x;
    const int tid = threadIdx.x;
    const int wv = tid >> 6, ln = tid & 63;
    __shared__ float qh[H_ * D_];
    __shared__ float lg4[TC_][4];
    __shared__ float p4[TC_][4];
    __shared__ float vlds[32 * 128];
    __shared__ float sc[NS_];
    for (int i = tid; i < H_ * D_; i += 256) qh[i] = qkv[(size_t)t * QKV_N + i];
    if (tid < NS_) sc[tid] = 0.f;
    int nv = (t >= LL - 1) ? ((t - (LL - 1)) / SS + 1) : 0;
    if (nv > TC_) nv = TC_;
    const float g0 = gate[t * 3 + 0];
    __syncthreads();
    for (int kv = 0; kv < KVH; kv++) {
        // A: logits (4 heads sharing this kv), wave-per-c, lane pair over D
        for (int c = wv; c < nv; c += 4) {
            const float* kr = kcmp + ((size_t)c * KVH + kv) * D_;
            const float k0 = kr[2 * ln], k1 = kr[2 * ln + 1];
            float ah[4];
#pragma unroll
            for (int hh = 0; hh < 4; hh++) {
                const float* q = qh + (4 * kv + hh) * D_;
                ah[hh] = k0 * q[2 * ln] + k1 * q[2 * ln + 1];
            }
#pragma unroll
            for (int o = 32; o > 0; o >>= 1) {
#pragma unroll
                for (int hh = 0; hh < 4; hh++) ah[hh] += __shfl_xor(ah[hh], o);
            }
            if (ln == 0) {
#pragma unroll
                for (int hh = 0; hh < 4; hh++) lg4[c][hh] = ah[hh] * SCALE_;
            }
        }
        __syncthreads();
        // B: softmax per head (wave wv -> head 4*kv+wv), normalized in place
        {
            float m = -1e30f;
            for (int c = ln; c < nv; c += 64) m = fmaxf(m, lg4[c][wv]);
#pragma unroll
            for (int o = 32; o > 0; o >>= 1) m = fmaxf(m, __shfl_xor(m, o));
            float s = 0.f;
            for (int c = ln; c < nv; c += 64) {
                const float p = expf(lg4[c][wv] - m);
                p4[c][wv] = p;
                s += p;
            }
#pragma unroll
            for (int o = 32; o > 0; o >>= 1) s += __shfl_xor(s, o);
            const float inv = (s > 0.f) ? 1.f / s : 0.f;
            for (int c = ln; c < nv; c += 64) p4[c][wv] *= inv;
        }
        __syncthreads();
        // C: o_cmp = p @ v_cmp, v rows staged in LDS, reused by 4 heads
        {
            const int d = tid & 127, hb = tid >> 7;   // hb in {0,1}
            float a0 = 0.f, a1 = 0.f;
            for (int cc = 0; cc < nv; cc += 32) {
                const int nc = min(32, nv - cc);
                for (int i = tid; i < nc * 128; i += 256)
                    vlds[i] = vcmp[((size_t)(cc + (i >> 7)) * KVH + kv) * D_ + (i & 127)];
                __syncthreads();
                for (int ci = 0; ci < nc; ci++) {
                    const float v = vlds[ci * 128 + d];
                    a0 += p4[cc + ci][hb] * v;
                    a1 += p4[cc + ci][hb + 2] * v;
                }
                __syncthreads();
            }
            obuf[(size_t)t * (H_ * D_) + (4 * kv + hb) * D_ + d] = g0 * a0;
            obuf[(size_t)t * (H_ * D_) + (4 * kv + hb + 2) * D_ + d] = g0 * a1;
        }
        // D: block scores (ov overlap: c in [4j-1, 4j+3]) summed over the 4 heads
        if (tid < NS_) {
            const int j = tid;
            int clo = 4 * j - 1;
            if (clo < 0) clo = 0;
            int chi = 4 * j + 3;
            if (chi > nv - 1) chi = nv - 1;
            float s = 0.f;
            for (int c = clo; c <= chi; c++) s += p4[c][0] + p4[c][1] + p4[c][2] + p4[c][3];
            sc[j] += s;
        }
        __syncthreads();
    }
    // top-k selection -> bitmask (matches lax.top_k stable tie-breaking)
    if (tid == 0) {
        const int cur = t >> 6;
        unsigned int chosen = 0;
        for (int it = 0; it < TOPK_ - 3; it++) {
            float best = 0.f;
            int bj = -1;
            for (int j = 0; j < NS_; j++) {
                if ((chosen >> j) & 1u) continue;
                const float v = (j >= cur) ? -INFINITY : sc[j];
                if (bj < 0 || v > best) { best = v; bj = j; }
            }
            chosen |= 1u << bj;
        }
        int f1 = cur - 2; if (f1 < 0) f1 = 0;
        int f2 = cur - 1; if (f2 < 0) f2 = 0;
        chosen |= 1u | (1u << f1) | (1u << f2) | (1u << cur);
        amask[t] = chosen;
    }
}

// ---------------------------------------------------------------------------
// SLC + SWA fused flash-style attention. One block per (64-query tile, head).
// Online softmax with two masked streams over shared QK^T logits.
// ---------------------------------------------------------------------------
DEV void stream_step(const float lgv[4][4], float m[4], float lsum[4], f32x4 acc[8],
                     unsigned short* PsW, const unsigned short* VtS, int l) {
    const int lc = l & 15, lg = l >> 4;
    float mn[4], scf[4], rs[4];
#pragma unroll
    for (int r = 0; r < 4; r++) {
        float rm = fmaxf(fmaxf(lgv[0][r], lgv[1][r]), fmaxf(lgv[2][r], lgv[3][r]));
#pragma unroll
        for (int o = 1; o < 16; o <<= 1) rm = fmaxf(rm, __shfl_xor(rm, o));
        mn[r] = fmaxf(m[r], rm);
        scf[r] = expf(m[r] - mn[r]);
        m[r] = mn[r];
        rs[r] = 0.f;
    }
    float pv[4][4];
#pragma unroll
    for (int kt = 0; kt < 4; kt++)
#pragma unroll
        for (int r = 0; r < 4; r++) {
            const float p = (lgv[kt][r] <= -1e29f) ? 0.f : expf(lgv[kt][r] - mn[r]);
            pv[kt][r] = p;
            rs[r] += p;
        }
#pragma unroll
    for (int r = 0; r < 4; r++) {
#pragma unroll
        for (int o = 1; o < 16; o <<= 1) rs[r] += __shfl_xor(rs[r], o);
        lsum[r] = lsum[r] * scf[r] + rs[r];
    }
#pragma unroll
    for (int j = 0; j < 8; j++)
#pragma unroll
        for (int r = 0; r < 4; r++) acc[j][r] *= scf[r];
    // write P (bf16, swizzled), then PV
#pragma unroll
    for (int kt = 0; kt < 4; kt++)
#pragma unroll
        for (int r = 0; r < 4; r++) {
            const int row = lg * 4 + r;
            const int col = kt * 16 + lc;
            PsW[row * 64 + (col ^ ((row & 7) << 3))] = f2b(pv[kt][r]);
        }
    __syncthreads();
#pragma unroll
    for (int ks2 = 0; ks2 < 2; ks2++) {
        short8 af = *(const short8*)&PsW[lc * 64 + ((ks2 * 32 + lg * 8) ^ ((lc & 7) << 3))];
#pragma unroll
        for (int j = 0; j < 8; j++) {
            const int dd = j * 16 + lc;
            short8 bf = *(const short8*)&VtS[dd * 64 + ((ks2 * 32 + lg * 8) ^ ((dd & 7) << 3))];
            acc[j] = __builtin_amdgcn_mfma_f32_16x16x32_bf16(af, bf, acc[j], 0, 0, 0);
        }
    }
    __syncthreads();
}

__global__ __launch_bounds__(256) void slc_swa(const unsigned short* __restrict__ qkvb,
                                               const unsigned int* __restrict__ amask,
                                               const float* __restrict__ gate,
                                               const float* __restrict__ sinks,
                                               float* __restrict__ obuf) {
    const int qb = blockIdx.x;   // 0..31 (64-query tile)
    const int h = blockIdx.y;    // 0..15
    const int t0 = qb * 64;
    const int cur = qb;
    const int kv = h >> 2;
    const int tid = threadIdx.x;
    const int w = tid >> 6, l = tid & 63;
    const int lc = l & 15, lg = l >> 4;

    __shared__ __align__(16) unsigned short Ks[64 * 128];
    __shared__ __align__(16) unsigned short Vt[128 * 64];
    __shared__ __align__(16) unsigned short Ps[4][16 * 64];
    __shared__ unsigned int am[64];
    __shared__ unsigned int uni_s;

    if (tid < 64) am[tid] = amask[t0 + tid];
    __syncthreads();
    if (tid == 0) {
        unsigned int u = 0;
        for (int i = 0; i < 64; i++) u |= am[i];
        uni_s = u;
    }
    __syncthreads();
    const unsigned int uni = uni_s;

    int tq[4];
    unsigned int amr[4];
#pragma unroll
    for (int r = 0; r < 4; r++) {
        const int rl = w * 16 + lg * 4 + r;
        tq[r] = t0 + rl;
        amr[r] = am[rl];
    }

    // Q fragments (A operand), straight from global bf16
    short8 aq[4];
    {
        const unsigned short* qp = qkvb + (size_t)(t0 + w * 16 + lc) * QKV_N + h * D_ + lg * 8;
#pragma unroll
        for (int ks = 0; ks < 4; ks++) aq[ks] = *(const short8*)(qp + ks * 32);
    }

    f32x4 acc_s[8] = {};
    f32x4 acc_w[8] = {};
    float m_s[4], l_s[4], m_w[4], l_w[4];
#pragma unroll
    for (int r = 0; r < 4; r++) { m_s[r] = -1e30f; l_s[r] = 0.f; m_w[r] = -1e30f; l_w[r] = 0.f; }

    const int kcol0 = H_ * D_ + kv * D_;
    const int vcol0 = H_ * D_ + KVH * D_ + kv * D_;

    for (int jb = 0; jb <= cur; jb++) {
        const bool slc_on = (uni >> jb) & 1u;
        const bool swa_on = (jb * 64 + 63) > (t0 - WIN_);
        if (!slc_on && !swa_on) continue;
        __syncthreads();
        // stage K [64 keys x 128] and V^T [128 d x 64 keys], both XOR-swizzled
        {
            const int d0 = (tid & 15) * 8;
            const int kk = tid >> 4;
#pragma unroll
            for (int mIt = 0; mIt < 4; mIt++) {
                const int kk2 = kk + mIt * 16;
                const size_t row = (size_t)(jb * 64 + kk2) * QKV_N;
                short8 kvals = *(const short8*)(qkvb + row + kcol0 + d0);
                *(short8*)&Ks[kk2 * 128 + (d0 ^ ((kk2 & 7) << 3))] = kvals;
                short8 vvals = *(const short8*)(qkvb + row + vcol0 + d0);
#pragma unroll
                for (int j = 0; j < 8; j++) {
                    const int dd = d0 + j;
                    Vt[dd * 64 + (kk2 ^ ((dd & 7) << 3))] = (unsigned short)vvals[j];
                }
            }
        }
        __syncthreads();
        // S = Q K^T  (4 key sub-tiles of 16)
        f32x4 sfr[4] = {};
#pragma unroll
        for (int kt = 0; kt < 4; kt++) {
            const int key = kt * 16 + lc;
#pragma unroll
            for (int ks = 0; ks < 4; ks++) {
                short8 bf = *(const short8*)&Ks[key * 128 + ((ks * 32 + lg * 8) ^ ((key & 7) << 3))];
                sfr[kt] = __builtin_amdgcn_mfma_f32_16x16x32_bf16(aq[ks], bf, sfr[kt], 0, 0, 0);
            }
        }
        float base[4][4];
#pragma unroll
        for (int kt = 0; kt < 4; kt++)
#pragma unroll
            for (int r = 0; r < 4; r++) base[kt][r] = sfr[kt][r] * SCALE_;

        if (slc_on) {
            float lgv[4][4];
#pragma unroll
            for (int kt = 0; kt < 4; kt++) {
                const int kpos = jb * 64 + kt * 16 + lc;
#pragma unroll
                for (int r = 0; r < 4; r++) {
                    const bool ok = (kpos <= tq[r]) && ((amr[r] >> jb) & 1u);
                    lgv[kt][r] = ok ? base[kt][r] : -1e30f;
                }
            }
            stream_step(lgv, m_s, l_s, acc_s, Ps[w], Vt, l);
        }
        if (swa_on) {
            float lgv[4][4];
#pragma unroll
            for (int kt = 0; kt < 4; kt++) {
                const int kpos = jb * 64 + kt * 16 + lc;
#pragma unroll
                for (int r = 0; r < 4; r++) {
                    const bool ok = (kpos <= tq[r]) && (kpos > tq[r] - WIN_);
                    lgv[kt][r] = ok ? base[kt][r] : -1e30f;
                }
            }
            stream_step(lgv, m_w, l_w, acc_w, Ps[w], Vt, l);
        }
    }

    const float snk = sinks[h];
#pragma unroll
    for (int r = 0; r < 4; r++) {
        const int t = tq[r];
        const float g1 = gate[t * 3 + 1], g2 = gate[t * 3 + 2];
        const float invs = 1.f / l_s[r];
        const float Mx = fmaxf(m_w[r], snk);
        const float ew = expf(m_w[r] - Mx);
        const float fw = ew / (l_w[r] * ew + expf(snk - Mx));
#pragma unroll
        for (int j = 0; j < 8; j++) {
            const int dd = j * 16 + lc;
            const size_t idx = (size_t)t * (H_ * D_) + h * D_ + dd;
            obuf[idx] += g1 * acc_s[j][r] * invs + g2 * acc_w[j][r] * fw;
        }
    }
}

// ---------------------------------------------------------------------------
extern "C" void kernel_launch(void* const* d_in, const int* in_sizes, int n_in,
                              void* d_out, int out_size, void* d_ws, size_t ws_size,
                              hipStream_t stream) {
    const float* x = (const float*)d_in[0];
    const float* W_qkv = (const float*)d_in[1];
    const float* b_qkv = (const float*)d_in[2];
    const float* W_out = (const float*)d_in[3];
    const float* b_out = (const float*)d_in[4];
    const float* sinks = (const float*)d_in[5];
    const float* cmp_pos = (const float*)d_in[6];
    const float* W_c1 = (const float*)d_in[7];
    const float* b_c1 = (const float*)d_in[8];
    const float* W_c2 = (const float*)d_in[9];
    const float* b_c2 = (const float*)d_in[10];
    const float* W_g1 = (const float*)d_in[11];
    const float* b_g1 = (const float*)d_in[12];
    const float* W_g2 = (const float*)d_in[13];
    const float* b_g2 = (const float*)d_in[14];

    char* ws = (char*)d_ws;
    float* qkvf = (float*)(ws + 0);                          // 25,165,824 B
    unsigned short* qkvb = (unsigned short*)(ws + 25165824); // 12,582,912 B
    float* hgate = (float*)(ws + 37748736);                  //  4,194,304 B
    float* gateb = (float*)(ws + 41943040);                  //     24,576 B
    float* hk = (float*)(ws + 41967616);                     //    520,192 B
    float* hv = (float*)(ws + 42487808);                     //    520,192 B
    float* kcmp = (float*)(ws + 43008000);                   //    260,096 B
    float* vcmp = (float*)(ws + 43268096);                   //    260,096 B
    unsigned int* amaskb = (unsigned int*)(ws + 43528192);   //      8,192 B
    float* obuf = (float*)(ws + 43536384);                   // 16,777,216 B  (end 60,313,600)
    float* blkk = obuf;                                      // aliased: dead before obuf written
    float* blkv = obuf + (8323072 / 4);
    float* outf = (float*)d_out;

    // 1) qkv = x @ W_qkv^T + b  (f32 + bf16 copies)
    gemm_bt<0><<<dim3(QKV_N / 64, T_ / 64), 256, 0, stream>>>(x, W_qkv, b_qkv, qkvf, qkvb, T_, QKV_N, DIM_);
    // 2) gate hidden = gelu(x @ W_g1^T + b_g1)
    gemm_bt<1><<<dim3(GATE_HID_ / 64, T_ / 64), 256, 0, stream>>>(x, W_g1, b_g1, hgate, nullptr, T_, GATE_HID_, DIM_);
    // 3) gates
    gate2_k<<<dim3((T_ * 3 + 255) / 256), 256, 0, stream>>>(hgate, W_g2, b_g2, gateb);
    // 4) compression input blocks
    blk_build<<<dim3(2 * TC_ * KVH), 256, 0, stream>>>(qkvf, cmp_pos, blkk, blkv);
    // 5) compression layer 1 (gelu)
    gemm_bt<1><<<dim3(CMP_HID_ / 64, 8), 256, 0, stream>>>(blkk, W_c1, b_c1, hk, nullptr, TC_ * KVH, CMP_HID_, LL * D_);
    gemm_bt<1><<<dim3(CMP_HID_ / 64, 8), 256, 0, stream>>>(blkv, W_c1, b_c1, hv, nullptr, TC_ * KVH, CMP_HID_, LL * D_);
    // 6) compression layer 2
    gemm_bt<0><<<dim3(D_ / 64, 8), 256, 0, stream>>>(hk, W_c2, b_c2, kcmp, nullptr, TC_ * KVH, D_, CMP_HID_);
    gemm_bt<0><<<dim3(D_ / 64, 8), 256, 0, stream>>>(hv, W_c2, b_c2, vcmp, nullptr, TC_ * KVH, D_, CMP_HID_);
    // 7) CMP attention + block scores + top-k mask; obuf = g0*o_cmp
    cmp_attn<<<dim3(T_), 256, 0, stream>>>(qkvf, kcmp, vcmp, gateb, obuf, amaskb);
    // 8) SLC + SWA attention; obuf += g1*o_slc + g2*o_swa
    slc_swa<<<dim3(T_ / 64, H_), 256, 0, stream>>>(qkvb, amaskb, gateb, sinks, obuf);
    // 9) out = obuf @ W_out^T + b_out
    gemm_bt<0><<<dim3(DIM_ / 64, T_ / 64), 256, 0, stream>>>(obuf, W_out, b_out, outf, nullptr, T_, DIM_, H_ * D_);
}

// Round 2
// 873.006 us; speedup vs baseline: 1.2034x; 1.2034x over previous
//
#include <hip/hip_runtime.h>
#include <hip/hip_bf16.h>

#define DEV static __device__ __forceinline__

constexpr int T_ = 2048, DIM_ = 2048, H_ = 16, KVH = 4, D_ = 128;
constexpr int LL = 32, SS = 16, TOPK_ = 16, WIN_ = 512;
constexpr int GATE_HID_ = 512;
constexpr int TC_ = 127, NS_ = 32;
constexpr int QKV_N = (H_ + 2 * KVH) * D_;          // 3072
constexpr float SCALE_ = 0.08838834764831845f;       // D^-0.5

typedef __attribute__((ext_vector_type(8))) short short8;
typedef __attribute__((ext_vector_type(4))) float f32x4;
typedef __attribute__((ext_vector_type(4))) float float4v;
typedef __attribute__((ext_vector_type(4))) unsigned short u16x4;

DEV unsigned short f2b(float x) {
    return __builtin_bit_cast(unsigned short, __float2bfloat16(x));
}
DEV float b2f(unsigned short u) { return __builtin_bit_cast(float, ((unsigned)u) << 16); }
DEV float gelu_f(float x) { return 0.5f * x * (1.f + erff(x * 0.70710678118654752f)); }

DEV void g2l16(const void* g, void* l) {
    __builtin_amdgcn_global_load_lds((const __attribute__((address_space(1))) unsigned int*)g,
                                     (__attribute__((address_space(3))) unsigned int*)l, 16, 0, 0);
}

// ---------------------------------------------------------------------------
// f32 -> bf16 conversion (vectorized), n divisible by 4
// ---------------------------------------------------------------------------
__global__ void cvt_f2b(const float* __restrict__ s, unsigned short* __restrict__ d, int n) {
    const int i = (blockIdx.x * 256 + threadIdx.x) * 4;
    if (i >= n) return;
    float4v v = *(const float4v*)(s + i);
    u16x4 o;
#pragma unroll
    for (int j = 0; j < 4; j++) o[j] = f2b(v[j]);
    *(u16x4*)(d + i) = o;
}

// ---------------------------------------------------------------------------
// Fast bf16 GEMM, m97 structure: C = A @ B^T + bias. A:[M,K] bf16, B:[N,K] bf16.
// 128x128 tile, BK=32, 4 waves (2x2), global_load_lds width 16, linear LDS.
// M, N multiples of 128; K multiple of 32. ACT: 0 none, 1 exact gelu.
// ---------------------------------------------------------------------------
template <int ACT, bool WF, bool WB>
__global__ __launch_bounds__(256) void gemm_f(const unsigned short* __restrict__ A,
                                              const unsigned short* __restrict__ B,
                                              const float* __restrict__ bias,
                                              float* __restrict__ Cf,
                                              unsigned short* __restrict__ Cb,
                                              int M, int N, int K) {
    __shared__ __align__(16) unsigned short As[128 * 32];
    __shared__ __align__(16) unsigned short Bs[128 * 32];
    const int tid = threadIdx.x;
    const int w = tid >> 6, l = tid & 63;
    const int lc = l & 15, lg = l >> 4;
    const int wr = w >> 1, wc = w & 1;
    const int m0 = blockIdx.y * 128, n0 = blockIdx.x * 128;
    f32x4 acc[4][4] = {};
    for (int k0 = 0; k0 < K; k0 += 32) {
#pragma unroll
        for (int i = 0; i < 2; i++) {
            const int e = w * 64 + l + i * 256;          // 16B-group index
            const int row = e >> 2, cg = (e & 3) * 8;
            g2l16(A + (size_t)(m0 + row) * K + k0 + cg, As + w * 512 + i * 2048);
            g2l16(B + (size_t)(n0 + row) * K + k0 + cg, Bs + w * 512 + i * 2048);
        }
        __syncthreads();
        short8 af[4], bfr[4];
#pragma unroll
        for (int mi = 0; mi < 4; mi++)
            af[mi] = *(const short8*)&As[(wr * 64 + mi * 16 + lc) * 32 + lg * 8];
#pragma unroll
        for (int ni = 0; ni < 4; ni++)
            bfr[ni] = *(const short8*)&Bs[(wc * 64 + ni * 16 + lc) * 32 + lg * 8];
#pragma unroll
        for (int mi = 0; mi < 4; mi++)
#pragma unroll
            for (int ni = 0; ni < 4; ni++)
                acc[mi][ni] = __builtin_amdgcn_mfma_f32_16x16x32_bf16(af[mi], bfr[ni], acc[mi][ni], 0, 0, 0);
        __syncthreads();
    }
#pragma unroll
    for (int mi = 0; mi < 4; mi++) {
        const int gr = m0 + wr * 64 + mi * 16 + lg * 4;
#pragma unroll
        for (int ni = 0; ni < 4; ni++) {
            const int gc = n0 + wc * 64 + ni * 16 + lc;
            const float bv = bias[gc];
#pragma unroll
            for (int r = 0; r < 4; r++) {
                float v = acc[mi][ni][r] + bv;
                if (ACT == 1) v = gelu_f(v);
                const size_t idx = (size_t)(gr + r) * N + gc;
                if (WF) Cf[idx] = v;
                if (WB) Cb[idx] = f2b(v);
            }
        }
    }
}

// ---------------------------------------------------------------------------
// gate = sigmoid(hg @ W_g2^T + b_g2)
// ---------------------------------------------------------------------------
__global__ void gate2_k(const float* __restrict__ hg, const float* __restrict__ Wg2,
                        const float* __restrict__ bg2, float* __restrict__ gate) {
    const int idx = blockIdx.x * blockDim.x + threadIdx.x;
    if (idx >= T_ * 3) return;
    const int t = idx / 3, i = idx % 3;
    const float* h = hg + (size_t)t * GATE_HID_;
    const float* w = Wg2 + (size_t)i * GATE_HID_;
    float s = bg2[i];
    for (int j = 0; j < GATE_HID_; j++) s += h[j] * w[j];
    gate[idx] = 1.f / (1.f + expf(-s));
}

// ---------------------------------------------------------------------------
// Build compression inputs (bf16): blk[(which*1024+m)][l*D+d] = z + cmp_pos,
// rows m >= TC*KV zero-padded (M padded to 1024 per half for the 128-tile GEMM).
// ---------------------------------------------------------------------------
__global__ __launch_bounds__(256) void blk_build(const unsigned short* __restrict__ qkvb,
                                                 const float* __restrict__ cmp_pos,
                                                 unsigned short* __restrict__ blk) {
    const int b = blockIdx.x;                 // 0..2047
    const int which = b >> 10, m = b & 1023;
    unsigned short* dst = blk + ((size_t)(which * 1024 + m)) * (LL * D_);
    if (m >= TC_ * KVH) {
        for (int i = threadIdx.x; i < LL * D_; i += 256) dst[i] = 0;
        return;
    }
    const int c = m >> 2, kv = m & 3;
    const int col0 = H_ * D_ + which * KVH * D_ + kv * D_;
    for (int i = threadIdx.x; i < LL * D_; i += 256) {
        const int lrow = i >> 7, d = i & 127;
        const float v = b2f(qkvb[(size_t)(c * SS + lrow) * QKV_N + col0 + d]) + cmp_pos[i];
        dst[i] = f2b(v);
    }
}

// ---------------------------------------------------------------------------
// CMP attention (f32), block-score aggregation, top-k -> bitmask.
// obuf = g0 * o_cmp (initializes o). One block per query t (balanced remap).
// ---------------------------------------------------------------------------
__global__ __launch_bounds__(256) void cmp_attn(const unsigned short* __restrict__ qkvb,
                                                const float* __restrict__ kcmp,
                                                const float* __restrict__ vcmp,
                                                const float* __restrict__ gate,
                                                float* __restrict__ obuf,
                                                unsigned int* __restrict__ amask) {
    const int b = blockIdx.x;
    const int t = (b & 1) ? (b >> 1) : (T_ - 1 - (b >> 1));
    const int tid = threadIdx.x;
    const int wv = tid >> 6, ln = tid & 63;
    __shared__ float qh[H_ * D_];
    __shared__ float lg4[TC_][4];
    __shared__ float p4[TC_][4];
    __shared__ float vlds[32 * 128];
    __shared__ float sc[NS_];
    for (int i = tid; i < H_ * D_; i += 256) qh[i] = b2f(qkvb[(size_t)t * QKV_N + i]);
    if (tid < NS_) sc[tid] = 0.f;
    int nv = (t >= LL - 1) ? ((t - (LL - 1)) / SS + 1) : 0;
    if (nv > TC_) nv = TC_;
    const float g0 = gate[t * 3 + 0];
    __syncthreads();
    for (int kv = 0; kv < KVH; kv++) {
        for (int c = wv; c < nv; c += 4) {
            const float* kr = kcmp + ((size_t)c * KVH + kv) * D_;
            const float k0 = kr[2 * ln], k1 = kr[2 * ln + 1];
            float ah[4];
#pragma unroll
            for (int hh = 0; hh < 4; hh++) {
                const float* q = qh + (4 * kv + hh) * D_;
                ah[hh] = k0 * q[2 * ln] + k1 * q[2 * ln + 1];
            }
#pragma unroll
            for (int o = 32; o > 0; o >>= 1) {
#pragma unroll
                for (int hh = 0; hh < 4; hh++) ah[hh] += __shfl_xor(ah[hh], o);
            }
            if (ln == 0) {
#pragma unroll
                for (int hh = 0; hh < 4; hh++) lg4[c][hh] = ah[hh] * SCALE_;
            }
        }
        __syncthreads();
        {
            float m = -1e30f;
            for (int c = ln; c < nv; c += 64) m = fmaxf(m, lg4[c][wv]);
#pragma unroll
            for (int o = 32; o > 0; o >>= 1) m = fmaxf(m, __shfl_xor(m, o));
            float s = 0.f;
            for (int c = ln; c < nv; c += 64) {
                const float p = expf(lg4[c][wv] - m);
                p4[c][wv] = p;
                s += p;
            }
#pragma unroll
            for (int o = 32; o > 0; o >>= 1) s += __shfl_xor(s, o);
            const float inv = (s > 0.f) ? 1.f / s : 0.f;
            for (int c = ln; c < nv; c += 64) p4[c][wv] *= inv;
        }
        __syncthreads();
        {
            const int d = tid & 127, hb = tid >> 7;
            float a0 = 0.f, a1 = 0.f;
            for (int cc = 0; cc < nv; cc += 32) {
                const int nc = min(32, nv - cc);
                for (int i = tid; i < nc * 128; i += 256)
                    vlds[i] = vcmp[((size_t)(cc + (i >> 7)) * KVH + kv) * D_ + (i & 127)];
                __syncthreads();
                for (int ci = 0; ci < nc; ci++) {
                    const float v = vlds[ci * 128 + d];
                    a0 += p4[cc + ci][hb] * v;
                    a1 += p4[cc + ci][hb + 2] * v;
                }
                __syncthreads();
            }
            obuf[(size_t)t * (H_ * D_) + (4 * kv + hb) * D_ + d] = g0 * a0;
            obuf[(size_t)t * (H_ * D_) + (4 * kv + hb + 2) * D_ + d] = g0 * a1;
        }
        if (tid < NS_) {
            const int j = tid;
            int clo = 4 * j - 1;
            if (clo < 0) clo = 0;
            int chi = 4 * j + 3;
            if (chi > nv - 1) chi = nv - 1;
            float s = 0.f;
            for (int c = clo; c <= chi; c++) s += p4[c][0] + p4[c][1] + p4[c][2] + p4[c][3];
            sc[j] += s;
        }
        __syncthreads();
    }
    if (tid == 0) {
        const int cur = t >> 6;
        unsigned int chosen = 0;
        for (int it = 0; it < TOPK_ - 3; it++) {
            float best = 0.f;
            int bj = -1;
            for (int j = 0; j < NS_; j++) {
                if ((chosen >> j) & 1u) continue;
                const float v = (j >= cur) ? -INFINITY : sc[j];
                if (bj < 0 || v > best) { best = v; bj = j; }
            }
            chosen |= 1u << bj;
        }
        int f1 = cur - 2; if (f1 < 0) f1 = 0;
        int f2 = cur - 1; if (f2 < 0) f2 = 0;
        chosen |= 1u | (1u << f1) | (1u << f2) | (1u << cur);
        amask[t] = chosen;
    }
}

// ---------------------------------------------------------------------------
// SLC + SWA fused flash attention. Barriers only around K/V staging;
// P round-trip is wave-private (no __syncthreads in stream_step).
// ---------------------------------------------------------------------------
DEV void stream_step(const float lgv[4][4], float m[4], float lsum[4], f32x4 acc[8],
                     unsigned short* PsW, const unsigned short* VtS, int l) {
    const int lc = l & 15, lg = l >> 4;
    float mn[4], scf[4], rs[4];
    bool need = false;
#pragma unroll
    for (int r = 0; r < 4; r++) {
        float rm = fmaxf(fmaxf(lgv[0][r], lgv[1][r]), fmaxf(lgv[2][r], lgv[3][r]));
#pragma unroll
        for (int o = 1; o < 16; o <<= 1) rm = fmaxf(rm, __shfl_xor(rm, o));
        mn[r] = fmaxf(m[r], rm);
        scf[r] = __expf(m[r] - mn[r]);
        need |= (mn[r] > m[r]);
        m[r] = mn[r];
        rs[r] = 0.f;
    }
    float pv[4][4];
#pragma unroll
    for (int kt = 0; kt < 4; kt++)
#pragma unroll
        for (int r = 0; r < 4; r++) {
            const float p = (lgv[kt][r] <= -1e29f) ? 0.f : __expf(lgv[kt][r] - mn[r]);
            pv[kt][r] = p;
            rs[r] += p;
        }
#pragma unroll
    for (int r = 0; r < 4; r++) {
#pragma unroll
        for (int o = 1; o < 16; o <<= 1) rs[r] += __shfl_xor(rs[r], o);
        lsum[r] = lsum[r] * scf[r] + rs[r];
    }
    if (__any(need)) {
#pragma unroll
        for (int j = 0; j < 8; j++)
#pragma unroll
            for (int r = 0; r < 4; r++) acc[j][r] *= scf[r];
    }
#pragma unroll
    for (int kt = 0; kt < 4; kt++)
#pragma unroll
        for (int r = 0; r < 4; r++) {
            const int row = lg * 4 + r;
            const int col = kt * 16 + lc;
            PsW[row * 64 + (col ^ ((row & 7) << 3))] = f2b(pv[kt][r]);
        }
#pragma unroll
    for (int ks2 = 0; ks2 < 2; ks2++) {
        short8 af = *(const short8*)&PsW[lc * 64 + ((ks2 * 32 + lg * 8) ^ ((lc & 7) << 3))];
#pragma unroll
        for (int j = 0; j < 8; j++) {
            const int dd = j * 16 + lc;
            const int sdd = (((dd & 7) ^ ((dd >> 3) & 7)) << 3);
            short8 bf = *(const short8*)&VtS[dd * 64 + ((ks2 * 32 + lg * 8) ^ sdd)];
            acc[j] = __builtin_amdgcn_mfma_f32_16x16x32_bf16(af, bf, acc[j], 0, 0, 0);
        }
    }
}

__global__ __launch_bounds__(256) void slc_swa(const unsigned short* __restrict__ qkvb,
                                               const unsigned int* __restrict__ amask,
                                               const float* __restrict__ gate,
                                               const float* __restrict__ sinks,
                                               float* __restrict__ obuf) {
    const int bid = blockIdx.x;          // 512 blocks, balanced qb order
    const int h = bid & 15;
    const int xx = bid >> 4;
    const int qb = (xx & 1) ? (xx >> 1) : (31 - (xx >> 1));
    const int t0 = qb * 64;
    const int cur = qb;
    const int kv = h >> 2;
    const int tid = threadIdx.x;
    const int w = tid >> 6, l = tid & 63;
    const int lc = l & 15, lg = l >> 4;

    __shared__ __align__(16) unsigned short Ks[64 * 128];
    __shared__ __align__(16) unsigned short Vt[128 * 64];
    __shared__ __align__(16) unsigned short Ps[4][16 * 64];
    __shared__ unsigned int am[64];
    __shared__ unsigned int uni_s;

    if (tid < 64) am[tid] = amask[t0 + tid];
    __syncthreads();
    if (tid == 0) {
        unsigned int u = 0;
        for (int i = 0; i < 64; i++) u |= am[i];
        uni_s = u;
    }
    __syncthreads();
    const unsigned int uni = uni_s;

    int tq[4];
    unsigned int amr[4];
#pragma unroll
    for (int r = 0; r < 4; r++) {
        const int rl = w * 16 + lg * 4 + r;
        tq[r] = t0 + rl;
        amr[r] = am[rl];
    }

    short8 aq[4];
    {
        const unsigned short* qp = qkvb + (size_t)(t0 + w * 16 + lc) * QKV_N + h * D_ + lg * 8;
#pragma unroll
        for (int ks = 0; ks < 4; ks++) aq[ks] = *(const short8*)(qp + ks * 32);
    }

    f32x4 acc_s[8] = {};
    f32x4 acc_w[8] = {};
    float m_s[4], l_s[4], m_w[4], l_w[4];
#pragma unroll
    for (int r = 0; r < 4; r++) { m_s[r] = -1e30f; l_s[r] = 0.f; m_w[r] = -1e30f; l_w[r] = 0.f; }

    const int kcol0 = H_ * D_ + kv * D_;
    const int vcol0 = H_ * D_ + KVH * D_ + kv * D_;

    for (int jb = 0; jb <= cur; jb++) {
        const bool slc_on = (uni >> jb) & 1u;
        const bool swa_on = (jb * 64 + 63) > (t0 - WIN_);
        if (!slc_on && !swa_on) continue;
        __syncthreads();
        {
            const int d0 = (tid & 15) * 8;
            const int kk = tid >> 4;
#pragma unroll
            for (int mIt = 0; mIt < 4; mIt++) {
                const int kk2 = kk + mIt * 16;
                const size_t row = (size_t)(jb * 64 + kk2) * QKV_N;
                short8 kvals = *(const short8*)(qkvb + row + kcol0 + d0);
                *(short8*)&Ks[kk2 * 128 + (d0 ^ ((kk2 & 7) << 3))] = kvals;
                short8 vvals = *(const short8*)(qkvb + row + vcol0 + d0);
#pragma unroll
                for (int j = 0; j < 8; j++) {
                    const int dd = d0 + j;
                    const int sdd = (((dd & 7) ^ ((dd >> 3) & 7)) << 3);
                    Vt[dd * 64 + (kk2 ^ sdd)] = (unsigned short)vvals[j];
                }
            }
        }
        __syncthreads();
        f32x4 sfr[4] = {};
#pragma unroll
        for (int kt = 0; kt < 4; kt++) {
            const int key = kt * 16 + lc;
#pragma unroll
            for (int ks = 0; ks < 4; ks++) {
                short8 bf = *(const short8*)&Ks[key * 128 + ((ks * 32 + lg * 8) ^ ((key & 7) << 3))];
                sfr[kt] = __builtin_amdgcn_mfma_f32_16x16x32_bf16(aq[ks], bf, sfr[kt], 0, 0, 0);
            }
        }
        float base[4][4];
#pragma unroll
        for (int kt = 0; kt < 4; kt++)
#pragma unroll
            for (int r = 0; r < 4; r++) base[kt][r] = sfr[kt][r] * SCALE_;

        if (slc_on) {
            float lgv[4][4];
#pragma unroll
            for (int kt = 0; kt < 4; kt++) {
                const int kpos = jb * 64 + kt * 16 + lc;
#pragma unroll
                for (int r = 0; r < 4; r++) {
                    const bool ok = (kpos <= tq[r]) && ((amr[r] >> jb) & 1u);
                    lgv[kt][r] = ok ? base[kt][r] : -1e30f;
                }
            }
            stream_step(lgv, m_s, l_s, acc_s, Ps[w], Vt, l);
        }
        if (swa_on) {
            float lgv[4][4];
#pragma unroll
            for (int kt = 0; kt < 4; kt++) {
                const int kpos = jb * 64 + kt * 16 + lc;
#pragma unroll
                for (int r = 0; r < 4; r++) {
                    const bool ok = (kpos <= tq[r]) && (kpos > tq[r] - WIN_);
                    lgv[kt][r] = ok ? base[kt][r] : -1e30f;
                }
            }
            stream_step(lgv, m_w, l_w, acc_w, Ps[w], Vt, l);
        }
    }

    const float snk = sinks[h];
#pragma unroll
    for (int r = 0; r < 4; r++) {
        const int t = tq[r];
        const float g1 = gate[t * 3 + 1], g2 = gate[t * 3 + 2];
        const float invs = 1.f / l_s[r];
        const float Mx = fmaxf(m_w[r], snk);
        const float ew = __expf(m_w[r] - Mx);
        const float fw = ew / (l_w[r] * ew + __expf(snk - Mx));
#pragma unroll
        for (int j = 0; j < 8; j++) {
            const int dd = j * 16 + lc;
            const size_t idx = (size_t)t * (H_ * D_) + h * D_ + dd;
            obuf[idx] += g1 * acc_s[j][r] * invs + g2 * acc_w[j][r] * fw;
        }
    }
}

// ---------------------------------------------------------------------------
extern "C" void kernel_launch(void* const* d_in, const int* in_sizes, int n_in,
                              void* d_out, int out_size, void* d_ws, size_t ws_size,
                              hipStream_t stream) {
    const float* x = (const float*)d_in[0];
    const float* W_qkv = (const float*)d_in[1];
    const float* b_qkv = (const float*)d_in[2];
    const float* W_out = (const float*)d_in[3];
    const float* b_out = (const float*)d_in[4];
    const float* sinks = (const float*)d_in[5];
    const float* cmp_pos = (const float*)d_in[6];
    const float* W_c1 = (const float*)d_in[7];
    const float* b_c1 = (const float*)d_in[8];
    const float* W_c2 = (const float*)d_in[9];
    const float* b_c2 = (const float*)d_in[10];
    const float* W_g1 = (const float*)d_in[11];
    const float* b_g1 = (const float*)d_in[12];
    const float* W_g2 = (const float*)d_in[13];
    const float* b_g2 = (const float*)d_in[14];

    char* ws = (char*)d_ws;
    // region layout (lifetimes verified; total 37,781,504 B)
    unsigned short* qkvb = (unsigned short*)(ws + 0);          // 12,582,912  (steps 1-8)
    unsigned short* obufb = (unsigned short*)(ws + 0);         // reuses qkvb after slc_swa
    char* A0 = ws + 12582912;                                  // 16,777,216 region
    unsigned short* Wqkv_b = (unsigned short*)(A0);            // step 0-1
    float* hgate = (float*)(A0);                               // step 2-3
    unsigned short* Wg1_b = (unsigned short*)(A0 + 12582912);  // step 0-2
    unsigned short* blkb = (unsigned short*)(A0);              // steps 4-6 (2048x4096 bf16)
    float* obuf = (float*)(A0);                                // steps 7-9
    char* B0 = ws + 29360128;                                  // 8,388,608 region
    unsigned short* x_b = (unsigned short*)(B0);               // steps 0-2
    unsigned short* Wc1_b = (unsigned short*)(B0);             // steps 4-6
    unsigned short* Wc2_b = (unsigned short*)(B0 + 2097152);
    unsigned short* hc_b = (unsigned short*)(B0 + 2162688);    // 2048x256 bf16
    float* ccmp = (float*)(B0 + 3211264);                      // 2048x128 f32 (k rows 0..1023, v rows 1024..)
    unsigned short* Wout_b = (unsigned short*)(B0);            // steps 8-9
    float* gateb = (float*)(ws + 37748736);                    // 24,576
    unsigned int* amaskb = (unsigned int*)(ws + 37773312);     // 8,192
    float* outf = (float*)d_out;

    // 0) bf16 conversions for the early GEMMs
    cvt_f2b<<<dim3(4096), 256, 0, stream>>>(x, x_b, T_ * DIM_);
    cvt_f2b<<<dim3(6144), 256, 0, stream>>>(W_qkv, Wqkv_b, QKV_N * DIM_);
    cvt_f2b<<<dim3(1024), 256, 0, stream>>>(W_g1, Wg1_b, GATE_HID_ * DIM_);
    // 1) qkv (bf16 out)
    gemm_f<0, false, true><<<dim3(QKV_N / 128, T_ / 128), 256, 0, stream>>>(
        x_b, Wqkv_b, b_qkv, nullptr, qkvb, T_, QKV_N, DIM_);
    // 2) gate hidden = gelu(x @ W_g1^T + b_g1) (f32 out)
    gemm_f<1, true, false><<<dim3(GATE_HID_ / 128, T_ / 128), 256, 0, stream>>>(
        x_b, Wg1_b, b_g1, hgate, nullptr, T_, GATE_HID_, DIM_);
    // 3) gates
    gate2_k<<<dim3((T_ * 3 + 255) / 256), 256, 0, stream>>>(hgate, W_g2, b_g2, gateb);
    // 4) compression weights to bf16 (x_b dead now)
    cvt_f2b<<<dim3(1024), 256, 0, stream>>>(W_c1, Wc1_b, 256 * LL * D_);
    cvt_f2b<<<dim3(32), 256, 0, stream>>>(W_c2, Wc2_b, D_ * 256);
    // 5) compression inputs (k rows 0..1023 incl pad, v rows 1024..2047)
    blk_build<<<dim3(2048), 256, 0, stream>>>(qkvb, cmp_pos, blkb);
    // 6) compression MLP
    gemm_f<1, false, true><<<dim3(2, 16), 256, 0, stream>>>(
        blkb, Wc1_b, b_c1, nullptr, hc_b, 2048, 256, LL * D_);
    gemm_f<0, true, false><<<dim3(1, 16), 256, 0, stream>>>(
        hc_b, Wc2_b, b_c2, ccmp, nullptr, 2048, D_, 256);
    // 7) CMP attention + top-k mask; obuf = g0*o_cmp
    cmp_attn<<<dim3(T_), 256, 0, stream>>>(qkvb, ccmp, ccmp + 1024 * D_, gateb, obuf, amaskb);
    // 8) W_out to bf16 (ccmp dead); SLC+SWA
    cvt_f2b<<<dim3(4096), 256, 0, stream>>>(W_out, Wout_b, DIM_ * H_ * D_);
    slc_swa<<<dim3(512), 256, 0, stream>>>(qkvb, amaskb, gateb, sinks, obuf);
    // 9) o -> bf16 (qkvb dead), out = o @ W_out^T + b_out
    cvt_f2b<<<dim3(4096), 256, 0, stream>>>(obuf, obufb, T_ * H_ * D_);
    gemm_f<0, true, false><<<dim3(DIM_ / 128, T_ / 128), 256, 0, stream>>>(
        obufb, Wout_b, b_out, outf, nullptr, T_, DIM_, H_ * D_);
}

// Round 3
// 612.428 us; speedup vs baseline: 1.7155x; 1.4255x over previous
//
#include <hip/hip_runtime.h>
#include <hip/hip_bf16.h>

#define DEV static __device__ __forceinline__

constexpr int T_ = 2048, DIM_ = 2048, H_ = 16, KVH = 4, D_ = 128;
constexpr int LL = 32, SS = 16, TOPK_ = 16, WIN_ = 512;
constexpr int GATE_HID_ = 512;
constexpr int TC_ = 127, NS_ = 32;
constexpr int QKV_N = (H_ + 2 * KVH) * D_;          // 3072
constexpr float SCALE_ = 0.08838834764831845f;       // D^-0.5

typedef __attribute__((ext_vector_type(8))) short short8;
typedef __attribute__((ext_vector_type(4))) float f32x4;
typedef __attribute__((ext_vector_type(4))) float float4v;
typedef __attribute__((ext_vector_type(4))) unsigned short u16x4;

DEV unsigned short f2b(float x) {
    return __builtin_bit_cast(unsigned short, __float2bfloat16(x));
}
DEV float b2f(unsigned short u) { return __builtin_bit_cast(float, ((unsigned)u) << 16); }
DEV float gelu_f(float x) { return 0.5f * x * (1.f + erff(x * 0.70710678118654752f)); }

DEV void g2l16(const void* g, void* l) {
    __builtin_amdgcn_global_load_lds((const __attribute__((address_space(1))) unsigned int*)g,
                                     (__attribute__((address_space(3))) unsigned int*)l, 16, 0, 0);
}

// ---------------------------------------------------------------------------
// f32 -> bf16 conversion (vectorized), n divisible by 4
// ---------------------------------------------------------------------------
__global__ void cvt_f2b(const float* __restrict__ s, unsigned short* __restrict__ d, int n) {
    const int i = (blockIdx.x * 256 + threadIdx.x) * 4;
    if (i >= n) return;
    float4v v = *(const float4v*)(s + i);
    u16x4 o;
#pragma unroll
    for (int j = 0; j < 4; j++) o[j] = f2b(v[j]);
    *(u16x4*)(d + i) = o;
}

// ---------------------------------------------------------------------------
// Fast bf16 GEMM, m97 structure: C = A @ B^T + bias. A:[M,K] bf16, B:[N,K] bf16.
// ---------------------------------------------------------------------------
template <int ACT, bool WF, bool WB>
__global__ __launch_bounds__(256) void gemm_f(const unsigned short* __restrict__ A,
                                              const unsigned short* __restrict__ B,
                                              const float* __restrict__ bias,
                                              float* __restrict__ Cf,
                                              unsigned short* __restrict__ Cb,
                                              int M, int N, int K) {
    __shared__ __align__(16) unsigned short As[128 * 32];
    __shared__ __align__(16) unsigned short Bs[128 * 32];
    const int tid = threadIdx.x;
    const int w = tid >> 6, l = tid & 63;
    const int lc = l & 15, lg = l >> 4;
    const int wr = w >> 1, wc = w & 1;
    const int m0 = blockIdx.y * 128, n0 = blockIdx.x * 128;
    f32x4 acc[4][4] = {};
    for (int k0 = 0; k0 < K; k0 += 32) {
#pragma unroll
        for (int i = 0; i < 2; i++) {
            const int e = w * 64 + l + i * 256;          // 16B-group index
            const int row = e >> 2, cg = (e & 3) * 8;
            g2l16(A + (size_t)(m0 + row) * K + k0 + cg, As + w * 512 + i * 2048);
            g2l16(B + (size_t)(n0 + row) * K + k0 + cg, Bs + w * 512 + i * 2048);
        }
        __syncthreads();
        short8 af[4], bfr[4];
#pragma unroll
        for (int mi = 0; mi < 4; mi++)
            af[mi] = *(const short8*)&As[(wr * 64 + mi * 16 + lc) * 32 + lg * 8];
#pragma unroll
        for (int ni = 0; ni < 4; ni++)
            bfr[ni] = *(const short8*)&Bs[(wc * 64 + ni * 16 + lc) * 32 + lg * 8];
#pragma unroll
        for (int mi = 0; mi < 4; mi++)
#pragma unroll
            for (int ni = 0; ni < 4; ni++)
                acc[mi][ni] = __builtin_amdgcn_mfma_f32_16x16x32_bf16(af[mi], bfr[ni], acc[mi][ni], 0, 0, 0);
        __syncthreads();
    }
#pragma unroll
    for (int mi = 0; mi < 4; mi++) {
        const int gr = m0 + wr * 64 + mi * 16 + lg * 4;
#pragma unroll
        for (int ni = 0; ni < 4; ni++) {
            const int gc = n0 + wc * 64 + ni * 16 + lc;
            const float bv = bias[gc];
#pragma unroll
            for (int r = 0; r < 4; r++) {
                float v = acc[mi][ni][r] + bv;
                if (ACT == 1) v = gelu_f(v);
                const size_t idx = (size_t)(gr + r) * N + gc;
                if (WF) Cf[idx] = v;
                if (WB) Cb[idx] = f2b(v);
            }
        }
    }
}

// ---------------------------------------------------------------------------
// gate = sigmoid(hg @ W_g2^T + b_g2): one wave per (t,i)
// ---------------------------------------------------------------------------
__global__ __launch_bounds__(256) void gate2_k(const float* __restrict__ hg,
                                               const float* __restrict__ Wg2,
                                               const float* __restrict__ bg2,
                                               float* __restrict__ gate) {
    const int gi = blockIdx.x * 4 + (threadIdx.x >> 6);
    if (gi >= T_ * 3) return;
    const int t = gi / 3, i = gi % 3;
    const int l = threadIdx.x & 63;
    const float* h = hg + (size_t)t * GATE_HID_;
    const float* w = Wg2 + (size_t)i * GATE_HID_;
    float s = 0.f;
#pragma unroll
    for (int j = 0; j < GATE_HID_ / 64; j++) s += h[l + j * 64] * w[l + j * 64];
#pragma unroll
    for (int o = 32; o > 0; o >>= 1) s += __shfl_xor(s, o);
    if (l == 0) gate[gi] = 1.f / (1.f + expf(-(s + bg2[i])));
}

// ---------------------------------------------------------------------------
// Build compression inputs (bf16), rows m >= TC*KV zero-padded.
// ---------------------------------------------------------------------------
__global__ __launch_bounds__(256) void blk_build(const unsigned short* __restrict__ qkvb,
                                                 const float* __restrict__ cmp_pos,
                                                 unsigned short* __restrict__ blk) {
    const int b = blockIdx.x;                 // 0..2047
    const int which = b >> 10, m = b & 1023;
    unsigned short* dst = blk + ((size_t)(which * 1024 + m)) * (LL * D_);
    if (m >= TC_ * KVH) {
        for (int i = threadIdx.x; i < LL * D_; i += 256) dst[i] = 0;
        return;
    }
    const int c = m >> 2, kv = m & 3;
    const int col0 = H_ * D_ + which * KVH * D_ + kv * D_;
    for (int i = threadIdx.x; i < LL * D_; i += 256) {
        const int lrow = i >> 7, d = i & 127;
        const float v = b2f(qkvb[(size_t)(c * SS + lrow) * QKV_N + col0 + d]) + cmp_pos[i];
        dst[i] = f2b(v);
    }
}

// ---------------------------------------------------------------------------
// CMP attention v2 (MFMA). Block = (16-query tile, kv group); wave = head.
// Logits via MFMA (f32 accum), exact f32 softmax (single pass, all c in one
// N=128 tile), normalized p in f32 LDS for block scores, PV via bf16 MFMA.
// Writes obuf = g0*o_cmp and per-kv block-score slices scg[kv][t][j].
// ---------------------------------------------------------------------------
__global__ __launch_bounds__(256) void cmp_attn2(const unsigned short* __restrict__ qkvb,
                                                 const unsigned short* __restrict__ kcmpb,
                                                 const unsigned short* __restrict__ vcmpb,
                                                 const float* __restrict__ gate,
                                                 float* __restrict__ obuf,
                                                 float* __restrict__ scg) {
    const int bid = blockIdx.x;               // 512 blocks
    const int kv = bid & 3;
    const int tx = bid >> 2;                  // 0..127
    const int tt = (tx & 1) ? (tx >> 1) : (127 - (tx >> 1));   // balance
    const int t0 = tt * 16;
    const int tid = threadIdx.x;
    const int w = tid >> 6, l = tid & 63;
    const int lc = l & 15, lg = l >> 4;
    const int h = kv * 4 + w;

    __shared__ float pbuf[4][16][132];
    __shared__ __align__(16) unsigned short Vt[128 * 128];   // [d][c], XOR-swizzled

    // ---- stage V^T (cooperative, scatter with write/read swizzle) ----
    {
        const int d0 = (tid & 15) * 8;
        const int cb = tid >> 4;
#pragma unroll
        for (int ci = 0; ci < 8; ci++) {
            const int c = cb + ci * 16;       // 0..127
            short8 vv = *(const short8*)(vcmpb + ((size_t)(c * 4 + kv)) * D_ + d0);
#pragma unroll
            for (int j = 0; j < 8; j++) {
                const int dd = d0 + j;
                const int sw = (((dd & 7) ^ ((dd >> 3) & 7)) << 3);
                Vt[dd * 128 + (c ^ sw)] = (unsigned short)vv[j];
            }
        }
    }

    // ---- Q fragments ----
    short8 aq[4];
    {
        const unsigned short* qp = qkvb + (size_t)(t0 + lc) * QKV_N + h * D_ + lg * 8;
#pragma unroll
        for (int ks = 0; ks < 4; ks++) aq[ks] = *(const short8*)(qp + ks * 32);
    }

    // ---- logits: S[16 t][128 c] via MFMA, K frags straight from L2 ----
    f32x4 sfr[8] = {};
#pragma unroll
    for (int nj = 0; nj < 8; nj++) {
        const int c = nj * 16 + lc;
        const unsigned short* kp = kcmpb + ((size_t)(c * 4 + kv)) * D_ + lg * 8;
#pragma unroll
        for (int ks = 0; ks < 4; ks++) {
            short8 bf = *(const short8*)(kp + ks * 32);
            sfr[nj] = __builtin_amdgcn_mfma_f32_16x16x32_bf16(aq[ks], bf, sfr[nj], 0, 0, 0);
        }
    }

    // ---- exact f32 softmax per row (row spread over 16 lanes x 8 regs) ----
#pragma unroll
    for (int r = 0; r < 4; r++) {
        const int t = t0 + lg * 4 + r;
        const int nv = (t >= LL - 1) ? ((t - (LL - 1)) >> 4) + 1 : 0;
        float lv[8], mx = -1e30f;
#pragma unroll
        for (int nj = 0; nj < 8; nj++) {
            const int c = nj * 16 + lc;
            const float v = (c < nv) ? sfr[nj][r] * SCALE_ : -1e30f;
            lv[nj] = v;
            mx = fmaxf(mx, v);
        }
#pragma unroll
        for (int o = 1; o < 16; o <<= 1) mx = fmaxf(mx, __shfl_xor(mx, o));
        float s = 0.f, pe[8];
#pragma unroll
        for (int nj = 0; nj < 8; nj++) {
            const float e = (lv[nj] > -1e29f) ? __expf(lv[nj] - mx) : 0.f;
            pe[nj] = e;
            s += e;
        }
#pragma unroll
        for (int o = 1; o < 16; o <<= 1) s += __shfl_xor(s, o);
        const float inv = (s > 0.f) ? 1.f / s : 0.f;
#pragma unroll
        for (int nj = 0; nj < 8; nj++) sfr[nj][r] = pe[nj] * inv;
    }

    // ---- store p to LDS (per-wave buffer) ----
#pragma unroll
    for (int nj = 0; nj < 8; nj++)
#pragma unroll
        for (int r = 0; r < 4; r++) pbuf[w][lg * 4 + r][nj * 16 + lc] = sfr[nj][r];

    __syncthreads();   // pbuf (cross-wave for scores) + Vt ready

    // ---- block scores: sc[t][j] = sum_h ( p[4j..4j+3] + p[4j-1] ) ----
    for (int idx = tid; idx < 16 * NS_; idx += 256) {
        const int lt = idx >> 5, j = idx & 31;
        int clo = 4 * j - 1;
        if (clo < 0) clo = 0;
        const int chi = 4 * j + 3;   // <=127, p=0 at invalid c
        float s = 0.f;
        for (int c = clo; c <= chi; c++)
            s += pbuf[0][lt][c] + pbuf[1][lt][c] + pbuf[2][lt][c] + pbuf[3][lt][c];
        scg[((size_t)kv * T_ + (t0 + lt)) * NS_ + j] = s;
    }

    // ---- PV: A = p (bf16 from own pbuf), B = Vt ----
    short8 pa[4];
#pragma unroll
    for (int ks = 0; ks < 4; ks++) {
        const float* pr = &pbuf[w][lc][ks * 32 + lg * 8];
        short8 t;
#pragma unroll
        for (int j = 0; j < 8; j++) t[j] = (short)f2b(pr[j]);
        pa[ks] = t;
    }
    f32x4 acc[8] = {};
#pragma unroll
    for (int nj = 0; nj < 8; nj++) {
        const int dd = nj * 16 + lc;
        const int sw = (((dd & 7) ^ ((dd >> 3) & 7)) << 3);
#pragma unroll
        for (int ks = 0; ks < 4; ks++) {
            short8 bf = *(const short8*)&Vt[dd * 128 + ((ks * 32 + lg * 8) ^ sw)];
            acc[nj] = __builtin_amdgcn_mfma_f32_16x16x32_bf16(pa[ks], bf, acc[nj], 0, 0, 0);
        }
    }

    // ---- write obuf = g0 * o_cmp ----
#pragma unroll
    for (int r = 0; r < 4; r++) {
        const int t = t0 + lg * 4 + r;
        const float g0 = gate[t * 3 + 0];
#pragma unroll
        for (int nj = 0; nj < 8; nj++)
            obuf[(size_t)t * (H_ * D_) + h * D_ + nj * 16 + lc] = g0 * acc[nj][r];
    }
}

// ---------------------------------------------------------------------------
// top-k block selection -> bitmask (deterministic sum over 4 kv slices)
// ---------------------------------------------------------------------------
__global__ __launch_bounds__(256) void topk_k(const float* __restrict__ scg,
                                              unsigned int* __restrict__ amask) {
    const int t = blockIdx.x * 256 + threadIdx.x;
    if (t >= T_) return;
    float sc[NS_];
#pragma unroll
    for (int j = 0; j < NS_; j++)
        sc[j] = scg[((size_t)0 * T_ + t) * NS_ + j] + scg[((size_t)1 * T_ + t) * NS_ + j] +
                scg[((size_t)2 * T_ + t) * NS_ + j] + scg[((size_t)3 * T_ + t) * NS_ + j];
    const int cur = t >> 6;
    unsigned int chosen = 0;
    for (int it = 0; it < TOPK_ - 3; it++) {
        float best = 0.f;
        int bj = -1;
        for (int j = 0; j < NS_; j++) {
            if ((chosen >> j) & 1u) continue;
            const float v = (j >= cur) ? -INFINITY : sc[j];
            if (bj < 0 || v > best) { best = v; bj = j; }
        }
        chosen |= 1u << bj;
    }
    int f1 = cur - 2; if (f1 < 0) f1 = 0;
    int f2 = cur - 1; if (f2 < 0) f2 = 0;
    chosen |= 1u | (1u << f1) | (1u << f2) | (1u << cur);
    amask[t] = chosen;
}

// ---------------------------------------------------------------------------
// SLC + SWA fused flash attention (unchanged from round 2)
// ---------------------------------------------------------------------------
DEV void stream_step(const float lgv[4][4], float m[4], float lsum[4], f32x4 acc[8],
                     unsigned short* PsW, const unsigned short* VtS, int l) {
    const int lc = l & 15, lg = l >> 4;
    float mn[4], scf[4], rs[4];
    bool need = false;
#pragma unroll
    for (int r = 0; r < 4; r++) {
        float rm = fmaxf(fmaxf(lgv[0][r], lgv[1][r]), fmaxf(lgv[2][r], lgv[3][r]));
#pragma unroll
        for (int o = 1; o < 16; o <<= 1) rm = fmaxf(rm, __shfl_xor(rm, o));
        mn[r] = fmaxf(m[r], rm);
        scf[r] = __expf(m[r] - mn[r]);
        need |= (mn[r] > m[r]);
        m[r] = mn[r];
        rs[r] = 0.f;
    }
    float pv[4][4];
#pragma unroll
    for (int kt = 0; kt < 4; kt++)
#pragma unroll
        for (int r = 0; r < 4; r++) {
            const float p = (lgv[kt][r] <= -1e29f) ? 0.f : __expf(lgv[kt][r] - mn[r]);
            pv[kt][r] = p;
            rs[r] += p;
        }
#pragma unroll
    for (int r = 0; r < 4; r++) {
#pragma unroll
        for (int o = 1; o < 16; o <<= 1) rs[r] += __shfl_xor(rs[r], o);
        lsum[r] = lsum[r] * scf[r] + rs[r];
    }
    if (__any(need)) {
#pragma unroll
        for (int j = 0; j < 8; j++)
#pragma unroll
            for (int r = 0; r < 4; r++) acc[j][r] *= scf[r];
    }
#pragma unroll
    for (int kt = 0; kt < 4; kt++)
#pragma unroll
        for (int r = 0; r < 4; r++) {
            const int row = lg * 4 + r;
            const int col = kt * 16 + lc;
            PsW[row * 64 + (col ^ ((row & 7) << 3))] = f2b(pv[kt][r]);
        }
#pragma unroll
    for (int ks2 = 0; ks2 < 2; ks2++) {
        short8 af = *(const short8*)&PsW[lc * 64 + ((ks2 * 32 + lg * 8) ^ ((lc & 7) << 3))];
#pragma unroll
        for (int j = 0; j < 8; j++) {
            const int dd = j * 16 + lc;
            const int sdd = (((dd & 7) ^ ((dd >> 3) & 7)) << 3);
            short8 bf = *(const short8*)&VtS[dd * 64 + ((ks2 * 32 + lg * 8) ^ sdd)];
            acc[j] = __builtin_amdgcn_mfma_f32_16x16x32_bf16(af, bf, acc[j], 0, 0, 0);
        }
    }
}

__global__ __launch_bounds__(256) void slc_swa(const unsigned short* __restrict__ qkvb,
                                               const unsigned int* __restrict__ amask,
                                               const float* __restrict__ gate,
                                               const float* __restrict__ sinks,
                                               float* __restrict__ obuf) {
    const int bid = blockIdx.x;          // 512 blocks, balanced qb order
    const int h = bid & 15;
    const int xx = bid >> 4;
    const int qb = (xx & 1) ? (xx >> 1) : (31 - (xx >> 1));
    const int t0 = qb * 64;
    const int cur = qb;
    const int kv = h >> 2;
    const int tid = threadIdx.x;
    const int w = tid >> 6, l = tid & 63;
    const int lc = l & 15, lg = l >> 4;

    __shared__ __align__(16) unsigned short Ks[64 * 128];
    __shared__ __align__(16) unsigned short Vt[128 * 64];
    __shared__ __align__(16) unsigned short Ps[4][16 * 64];
    __shared__ unsigned int am[64];
    __shared__ unsigned int uni_s;

    if (tid < 64) am[tid] = amask[t0 + tid];
    __syncthreads();
    if (tid == 0) {
        unsigned int u = 0;
        for (int i = 0; i < 64; i++) u |= am[i];
        uni_s = u;
    }
    __syncthreads();
    const unsigned int uni = uni_s;

    int tq[4];
    unsigned int amr[4];
#pragma unroll
    for (int r = 0; r < 4; r++) {
        const int rl = w * 16 + lg * 4 + r;
        tq[r] = t0 + rl;
        amr[r] = am[rl];
    }

    short8 aq[4];
    {
        const unsigned short* qp = qkvb + (size_t)(t0 + w * 16 + lc) * QKV_N + h * D_ + lg * 8;
#pragma unroll
        for (int ks = 0; ks < 4; ks++) aq[ks] = *(const short8*)(qp + ks * 32);
    }

    f32x4 acc_s[8] = {};
    f32x4 acc_w[8] = {};
    float m_s[4], l_s[4], m_w[4], l_w[4];
#pragma unroll
    for (int r = 0; r < 4; r++) { m_s[r] = -1e30f; l_s[r] = 0.f; m_w[r] = -1e30f; l_w[r] = 0.f; }

    const int kcol0 = H_ * D_ + kv * D_;
    const int vcol0 = H_ * D_ + KVH * D_ + kv * D_;

    for (int jb = 0; jb <= cur; jb++) {
        const bool slc_on = (uni >> jb) & 1u;
        const bool swa_on = (jb * 64 + 63) > (t0 - WIN_);
        if (!slc_on && !swa_on) continue;
        __syncthreads();
        {
            const int d0 = (tid & 15) * 8;
            const int kk = tid >> 4;
#pragma unroll
            for (int mIt = 0; mIt < 4; mIt++) {
                const int kk2 = kk + mIt * 16;
                const size_t row = (size_t)(jb * 64 + kk2) * QKV_N;
                short8 kvals = *(const short8*)(qkvb + row + kcol0 + d0);
                *(short8*)&Ks[kk2 * 128 + (d0 ^ ((kk2 & 7) << 3))] = kvals;
                short8 vvals = *(const short8*)(qkvb + row + vcol0 + d0);
#pragma unroll
                for (int j = 0; j < 8; j++) {
                    const int dd = d0 + j;
                    const int sdd = (((dd & 7) ^ ((dd >> 3) & 7)) << 3);
                    Vt[dd * 64 + (kk2 ^ sdd)] = (unsigned short)vvals[j];
                }
            }
        }
        __syncthreads();
        f32x4 sfr[4] = {};
#pragma unroll
        for (int kt = 0; kt < 4; kt++) {
            const int key = kt * 16 + lc;
#pragma unroll
            for (int ks = 0; ks < 4; ks++) {
                short8 bf = *(const short8*)&Ks[key * 128 + ((ks * 32 + lg * 8) ^ ((key & 7) << 3))];
                sfr[kt] = __builtin_amdgcn_mfma_f32_16x16x32_bf16(aq[ks], bf, sfr[kt], 0, 0, 0);
            }
        }
        float base[4][4];
#pragma unroll
        for (int kt = 0; kt < 4; kt++)
#pragma unroll
            for (int r = 0; r < 4; r++) base[kt][r] = sfr[kt][r] * SCALE_;

        if (slc_on) {
            float lgv[4][4];
#pragma unroll
            for (int kt = 0; kt < 4; kt++) {
                const int kpos = jb * 64 + kt * 16 + lc;
#pragma unroll
                for (int r = 0; r < 4; r++) {
                    const bool ok = (kpos <= tq[r]) && ((amr[r] >> jb) & 1u);
                    lgv[kt][r] = ok ? base[kt][r] : -1e30f;
                }
            }
            stream_step(lgv, m_s, l_s, acc_s, Ps[w], Vt, l);
        }
        if (swa_on) {
            float lgv[4][4];
#pragma unroll
            for (int kt = 0; kt < 4; kt++) {
                const int kpos = jb * 64 + kt * 16 + lc;
#pragma unroll
                for (int r = 0; r < 4; r++) {
                    const bool ok = (kpos <= tq[r]) && (kpos > tq[r] - WIN_);
                    lgv[kt][r] = ok ? base[kt][r] : -1e30f;
                }
            }
            stream_step(lgv, m_w, l_w, acc_w, Ps[w], Vt, l);
        }
    }

    const float snk = sinks[h];
#pragma unroll
    for (int r = 0; r < 4; r++) {
        const int t = tq[r];
        const float g1 = gate[t * 3 + 1], g2 = gate[t * 3 + 2];
        const float invs = 1.f / l_s[r];
        const float Mx = fmaxf(m_w[r], snk);
        const float ew = __expf(m_w[r] - Mx);
        const float fw = ew / (l_w[r] * ew + __expf(snk - Mx));
#pragma unroll
        for (int j = 0; j < 8; j++) {
            const int dd = j * 16 + lc;
            const size_t idx = (size_t)t * (H_ * D_) + h * D_ + dd;
            obuf[idx] += g1 * acc_s[j][r] * invs + g2 * acc_w[j][r] * fw;
        }
    }
}

// ---------------------------------------------------------------------------
extern "C" void kernel_launch(void* const* d_in, const int* in_sizes, int n_in,
                              void* d_out, int out_size, void* d_ws, size_t ws_size,
                              hipStream_t stream) {
    const float* x = (const float*)d_in[0];
    const float* W_qkv = (const float*)d_in[1];
    const float* b_qkv = (const float*)d_in[2];
    const float* W_out = (const float*)d_in[3];
    const float* b_out = (const float*)d_in[4];
    const float* sinks = (const float*)d_in[5];
    const float* cmp_pos = (const float*)d_in[6];
    const float* W_c1 = (const float*)d_in[7];
    const float* b_c1 = (const float*)d_in[8];
    const float* W_c2 = (const float*)d_in[9];
    const float* b_c2 = (const float*)d_in[10];
    const float* W_g1 = (const float*)d_in[11];
    const float* b_g1 = (const float*)d_in[12];
    const float* W_g2 = (const float*)d_in[13];
    const float* b_g2 = (const float*)d_in[14];

    char* ws = (char*)d_ws;
    unsigned short* qkvb = (unsigned short*)(ws + 0);          // 12,582,912  (steps 1-8)
    unsigned short* obufb = (unsigned short*)(ws + 0);         // reuses qkvb after slc_swa
    char* A0 = ws + 12582912;                                  // 16,777,216 region
    unsigned short* Wqkv_b = (unsigned short*)(A0);            // step 0-1
    float* hgate = (float*)(A0);                               // step 2-3
    unsigned short* Wg1_b = (unsigned short*)(A0 + 12582912);  // step 0-2
    unsigned short* blkb = (unsigned short*)(A0);              // steps 4-6 (2048x4096 bf16)
    float* obuf = (float*)(A0);                                // steps 7-9
    char* B0 = ws + 29360128;                                  // 8,388,608 region
    unsigned short* x_b = (unsigned short*)(B0);               // steps 0-2
    unsigned short* Wc1_b = (unsigned short*)(B0);             // steps 4-7
    unsigned short* Wc2_b = (unsigned short*)(B0 + 2097152);
    unsigned short* hc_b = (unsigned short*)(B0 + 2162688);    // 2048x256 bf16
    unsigned short* hcmpb = (unsigned short*)(B0 + 3211264);   // 2048x128 bf16 (k 0..1023, v 1024..)
    unsigned short* Wout_b = (unsigned short*)(B0);            // steps 8-9
    float* gateb = (float*)(ws + 37748736);                    // 24,576
    unsigned int* amaskb = (unsigned int*)(ws + 37773312);     // 8,192
    float* scg = (float*)(ws + 37781504);                      // 1,048,576 (4 kv slices)
    float* outf = (float*)d_out;

    // 0) bf16 conversions for the early GEMMs
    cvt_f2b<<<dim3(4096), 256, 0, stream>>>(x, x_b, T_ * DIM_);
    cvt_f2b<<<dim3(6144), 256, 0, stream>>>(W_qkv, Wqkv_b, QKV_N * DIM_);
    cvt_f2b<<<dim3(1024), 256, 0, stream>>>(W_g1, Wg1_b, GATE_HID_ * DIM_);
    // 1) qkv (bf16 out)
    gemm_f<0, false, true><<<dim3(QKV_N / 128, T_ / 128), 256, 0, stream>>>(
        x_b, Wqkv_b, b_qkv, nullptr, qkvb, T_, QKV_N, DIM_);
    // 2) gate hidden = gelu(x @ W_g1^T + b_g1) (f32 out)
    gemm_f<1, true, false><<<dim3(GATE_HID_ / 128, T_ / 128), 256, 0, stream>>>(
        x_b, Wg1_b, b_g1, hgate, nullptr, T_, GATE_HID_, DIM_);
    // 3) gates
    gate2_k<<<dim3(1536), 256, 0, stream>>>(hgate, W_g2, b_g2, gateb);
    // 4) compression weights to bf16 (x_b dead now)
    cvt_f2b<<<dim3(1024), 256, 0, stream>>>(W_c1, Wc1_b, 256 * LL * D_);
    cvt_f2b<<<dim3(32), 256, 0, stream>>>(W_c2, Wc2_b, D_ * 256);
    // 5) compression inputs (k rows 0..1023 incl pad, v rows 1024..2047)
    blk_build<<<dim3(2048), 256, 0, stream>>>(qkvb, cmp_pos, blkb);
    // 6) compression MLP (bf16 out)
    gemm_f<1, false, true><<<dim3(2, 16), 256, 0, stream>>>(
        blkb, Wc1_b, b_c1, nullptr, hc_b, 2048, 256, LL * D_);
    gemm_f<0, false, true><<<dim3(1, 16), 256, 0, stream>>>(
        hc_b, Wc2_b, b_c2, nullptr, hcmpb, 2048, D_, 256);
    // 7) CMP attention (MFMA) + block-score slices; obuf = g0*o_cmp
    cmp_attn2<<<dim3(512), 256, 0, stream>>>(qkvb, hcmpb, hcmpb + 1024 * D_, gateb, obuf, scg);
    // 8) top-k -> mask; W_out to bf16 (B0 dead after cmp_attn2); SLC+SWA
    topk_k<<<dim3(T_ / 256), 256, 0, stream>>>(scg, amaskb);
    cvt_f2b<<<dim3(4096), 256, 0, stream>>>(W_out, Wout_b, DIM_ * H_ * D_);
    slc_swa<<<dim3(512), 256, 0, stream>>>(qkvb, amaskb, gateb, sinks, obuf);
    // 9) o -> bf16 (qkvb dead), out = o @ W_out^T + b_out
    cvt_f2b<<<dim3(4096), 256, 0, stream>>>(obuf, obufb, T_ * H_ * D_);
    gemm_f<0, true, false><<<dim3(DIM_ / 128, T_ / 128), 256, 0, stream>>>(
        obufb, Wout_b, b_out, outf, nullptr, T_, DIM_, H_ * D_);
}

// Round 4
// 559.115 us; speedup vs baseline: 1.8790x; 1.0954x over previous
//
#include <hip/hip_runtime.h>
#include <hip/hip_bf16.h>

#define DEV static __device__ __forceinline__

constexpr int T_ = 2048, DIM_ = 2048, H_ = 16, KVH = 4, D_ = 128;
constexpr int LL = 32, SS = 16, TOPK_ = 16, WIN_ = 512;
constexpr int GATE_HID_ = 512;
constexpr int TC_ = 127, NS_ = 32;
constexpr int QKV_N = (H_ + 2 * KVH) * D_;          // 3072
constexpr float SCALE_ = 0.08838834764831845f;       // D^-0.5

typedef __attribute__((ext_vector_type(8))) short short8;
typedef __attribute__((ext_vector_type(4))) float f32x4;
typedef __attribute__((ext_vector_type(4))) float float4v;
typedef __attribute__((ext_vector_type(4))) unsigned short u16x4;

DEV unsigned short f2b(float x) {
    return __builtin_bit_cast(unsigned short, __float2bfloat16(x));
}
DEV float b2f(unsigned short u) { return __builtin_bit_cast(float, ((unsigned)u) << 16); }
DEV float gelu_f(float x) { return 0.5f * x * (1.f + erff(x * 0.70710678118654752f)); }

DEV void g2l16(const void* g, void* l) {
    __builtin_amdgcn_global_load_lds((const __attribute__((address_space(1))) unsigned int*)g,
                                     (__attribute__((address_space(3))) unsigned int*)l, 16, 0, 0);
}

// ---------------------------------------------------------------------------
// f32 -> bf16 conversion (vectorized), n divisible by 4
// ---------------------------------------------------------------------------
__global__ void cvt_f2b(const float* __restrict__ s, unsigned short* __restrict__ d, int n) {
    const int i = (blockIdx.x * 256 + threadIdx.x) * 4;
    if (i >= n) return;
    float4v v = *(const float4v*)(s + i);
    u16x4 o;
#pragma unroll
    for (int j = 0; j < 4; j++) o[j] = f2b(v[j]);
    *(u16x4*)(d + i) = o;
}

// ---------------------------------------------------------------------------
// Fast bf16 GEMM, m97 structure: C = A @ B^T + bias. A:[M,K] bf16, B:[N,K] bf16.
// ---------------------------------------------------------------------------
template <int ACT, bool WF, bool WB>
__global__ __launch_bounds__(256) void gemm_f(const unsigned short* __restrict__ A,
                                              const unsigned short* __restrict__ B,
                                              const float* __restrict__ bias,
                                              float* __restrict__ Cf,
                                              unsigned short* __restrict__ Cb,
                                              int M, int N, int K) {
    __shared__ __align__(16) unsigned short As[128 * 32];
    __shared__ __align__(16) unsigned short Bs[128 * 32];
    const int tid = threadIdx.x;
    const int w = tid >> 6, l = tid & 63;
    const int lc = l & 15, lg = l >> 4;
    const int wr = w >> 1, wc = w & 1;
    const int m0 = blockIdx.y * 128, n0 = blockIdx.x * 128;
    f32x4 acc[4][4] = {};
    for (int k0 = 0; k0 < K; k0 += 32) {
#pragma unroll
        for (int i = 0; i < 2; i++) {
            const int e = w * 64 + l + i * 256;          // 16B-group index
            const int row = e >> 2, cg = (e & 3) * 8;
            g2l16(A + (size_t)(m0 + row) * K + k0 + cg, As + w * 512 + i * 2048);
            g2l16(B + (size_t)(n0 + row) * K + k0 + cg, Bs + w * 512 + i * 2048);
        }
        __syncthreads();
        short8 af[4], bfr[4];
#pragma unroll
        for (int mi = 0; mi < 4; mi++)
            af[mi] = *(const short8*)&As[(wr * 64 + mi * 16 + lc) * 32 + lg * 8];
#pragma unroll
        for (int ni = 0; ni < 4; ni++)
            bfr[ni] = *(const short8*)&Bs[(wc * 64 + ni * 16 + lc) * 32 + lg * 8];
#pragma unroll
        for (int mi = 0; mi < 4; mi++)
#pragma unroll
            for (int ni = 0; ni < 4; ni++)
                acc[mi][ni] = __builtin_amdgcn_mfma_f32_16x16x32_bf16(af[mi], bfr[ni], acc[mi][ni], 0, 0, 0);
        __syncthreads();
    }
#pragma unroll
    for (int mi = 0; mi < 4; mi++) {
        const int gr = m0 + wr * 64 + mi * 16 + lg * 4;
#pragma unroll
        for (int ni = 0; ni < 4; ni++) {
            const int gc = n0 + wc * 64 + ni * 16 + lc;
            const float bv = bias[gc];
#pragma unroll
            for (int r = 0; r < 4; r++) {
                float v = acc[mi][ni][r] + bv;
                if (ACT == 1) v = gelu_f(v);
                const size_t idx = (size_t)(gr + r) * N + gc;
                if (WF) Cf[idx] = v;
                if (WB) Cb[idx] = f2b(v);
            }
        }
    }
}

// ---------------------------------------------------------------------------
// gate = sigmoid(hg @ W_g2^T + b_g2): one wave per (t,i)
// ---------------------------------------------------------------------------
__global__ __launch_bounds__(256) void gate2_k(const float* __restrict__ hg,
                                               const float* __restrict__ Wg2,
                                               const float* __restrict__ bg2,
                                               float* __restrict__ gate) {
    const int gi = blockIdx.x * 4 + (threadIdx.x >> 6);
    if (gi >= T_ * 3) return;
    const int t = gi / 3, i = gi % 3;
    const int l = threadIdx.x & 63;
    const float* h = hg + (size_t)t * GATE_HID_;
    const float* w = Wg2 + (size_t)i * GATE_HID_;
    float s = 0.f;
#pragma unroll
    for (int j = 0; j < GATE_HID_ / 64; j++) s += h[l + j * 64] * w[l + j * 64];
#pragma unroll
    for (int o = 32; o > 0; o >>= 1) s += __shfl_xor(s, o);
    if (l == 0) gate[gi] = 1.f / (1.f + expf(-(s + bg2[i])));
}

// ---------------------------------------------------------------------------
// Build compression inputs (bf16), rows m >= TC*KV zero-padded.
// ---------------------------------------------------------------------------
__global__ __launch_bounds__(256) void blk_build(const unsigned short* __restrict__ qkvb,
                                                 const float* __restrict__ cmp_pos,
                                                 unsigned short* __restrict__ blk) {
    const int b = blockIdx.x;                 // 0..2047
    const int which = b >> 10, m = b & 1023;
    unsigned short* dst = blk + ((size_t)(which * 1024 + m)) * (LL * D_);
    if (m >= TC_ * KVH) {
        for (int i = threadIdx.x; i < LL * D_; i += 256) dst[i] = 0;
        return;
    }
    const int c = m >> 2, kv = m & 3;
    const int col0 = H_ * D_ + which * KVH * D_ + kv * D_;
    for (int i = threadIdx.x; i < LL * D_; i += 256) {
        const int lrow = i >> 7, d = i & 127;
        const float v = b2f(qkvb[(size_t)(c * SS + lrow) * QKV_N + col0 + d]) + cmp_pos[i];
        dst[i] = f2b(v);
    }
}

// ---------------------------------------------------------------------------
// CMP attention v2 (MFMA) + block-score slices (unchanged from round 3)
// ---------------------------------------------------------------------------
__global__ __launch_bounds__(256) void cmp_attn2(const unsigned short* __restrict__ qkvb,
                                                 const unsigned short* __restrict__ kcmpb,
                                                 const unsigned short* __restrict__ vcmpb,
                                                 const float* __restrict__ gate,
                                                 float* __restrict__ obuf,
                                                 float* __restrict__ scg) {
    const int bid = blockIdx.x;               // 512 blocks
    const int kv = bid & 3;
    const int tx = bid >> 2;                  // 0..127
    const int tt = (tx & 1) ? (tx >> 1) : (127 - (tx >> 1));   // balance
    const int t0 = tt * 16;
    const int tid = threadIdx.x;
    const int w = tid >> 6, l = tid & 63;
    const int lc = l & 15, lg = l >> 4;
    const int h = kv * 4 + w;

    __shared__ float pbuf[4][16][132];
    __shared__ __align__(16) unsigned short Vt[128 * 128];   // [d][c], XOR-swizzled

    {
        const int d0 = (tid & 15) * 8;
        const int cb = tid >> 4;
#pragma unroll
        for (int ci = 0; ci < 8; ci++) {
            const int c = cb + ci * 16;       // 0..127
            short8 vv = *(const short8*)(vcmpb + ((size_t)(c * 4 + kv)) * D_ + d0);
#pragma unroll
            for (int j = 0; j < 8; j++) {
                const int dd = d0 + j;
                const int sw = (((dd & 7) ^ ((dd >> 3) & 7)) << 3);
                Vt[dd * 128 + (c ^ sw)] = (unsigned short)vv[j];
            }
        }
    }

    short8 aq[4];
    {
        const unsigned short* qp = qkvb + (size_t)(t0 + lc) * QKV_N + h * D_ + lg * 8;
#pragma unroll
        for (int ks = 0; ks < 4; ks++) aq[ks] = *(const short8*)(qp + ks * 32);
    }

    f32x4 sfr[8] = {};
#pragma unroll
    for (int nj = 0; nj < 8; nj++) {
        const int c = nj * 16 + lc;
        const unsigned short* kp = kcmpb + ((size_t)(c * 4 + kv)) * D_ + lg * 8;
#pragma unroll
        for (int ks = 0; ks < 4; ks++) {
            short8 bf = *(const short8*)(kp + ks * 32);
            sfr[nj] = __builtin_amdgcn_mfma_f32_16x16x32_bf16(aq[ks], bf, sfr[nj], 0, 0, 0);
        }
    }

#pragma unroll
    for (int r = 0; r < 4; r++) {
        const int t = t0 + lg * 4 + r;
        const int nv = (t >= LL - 1) ? ((t - (LL - 1)) >> 4) + 1 : 0;
        float lv[8], mx = -1e30f;
#pragma unroll
        for (int nj = 0; nj < 8; nj++) {
            const int c = nj * 16 + lc;
            const float v = (c < nv) ? sfr[nj][r] * SCALE_ : -1e30f;
            lv[nj] = v;
            mx = fmaxf(mx, v);
        }
#pragma unroll
        for (int o = 1; o < 16; o <<= 1) mx = fmaxf(mx, __shfl_xor(mx, o));
        float s = 0.f, pe[8];
#pragma unroll
        for (int nj = 0; nj < 8; nj++) {
            const float e = (lv[nj] > -1e29f) ? __expf(lv[nj] - mx) : 0.f;
            pe[nj] = e;
            s += e;
        }
#pragma unroll
        for (int o = 1; o < 16; o <<= 1) s += __shfl_xor(s, o);
        const float inv = (s > 0.f) ? 1.f / s : 0.f;
#pragma unroll
        for (int nj = 0; nj < 8; nj++) sfr[nj][r] = pe[nj] * inv;
    }

#pragma unroll
    for (int nj = 0; nj < 8; nj++)
#pragma unroll
        for (int r = 0; r < 4; r++) pbuf[w][lg * 4 + r][nj * 16 + lc] = sfr[nj][r];

    __syncthreads();

    for (int idx = tid; idx < 16 * NS_; idx += 256) {
        const int lt = idx >> 5, j = idx & 31;
        int clo = 4 * j - 1;
        if (clo < 0) clo = 0;
        const int chi = 4 * j + 3;
        float s = 0.f;
        for (int c = clo; c <= chi; c++)
            s += pbuf[0][lt][c] + pbuf[1][lt][c] + pbuf[2][lt][c] + pbuf[3][lt][c];
        scg[((size_t)kv * T_ + (t0 + lt)) * NS_ + j] = s;
    }

    short8 pa[4];
#pragma unroll
    for (int ks = 0; ks < 4; ks++) {
        const float* pr = &pbuf[w][lc][ks * 32 + lg * 8];
        short8 t;
#pragma unroll
        for (int j = 0; j < 8; j++) t[j] = (short)f2b(pr[j]);
        pa[ks] = t;
    }
    f32x4 acc[8] = {};
#pragma unroll
    for (int nj = 0; nj < 8; nj++) {
        const int dd = nj * 16 + lc;
        const int sw = (((dd & 7) ^ ((dd >> 3) & 7)) << 3);
#pragma unroll
        for (int ks = 0; ks < 4; ks++) {
            short8 bf = *(const short8*)&Vt[dd * 128 + ((ks * 32 + lg * 8) ^ sw)];
            acc[nj] = __builtin_amdgcn_mfma_f32_16x16x32_bf16(pa[ks], bf, acc[nj], 0, 0, 0);
        }
    }

#pragma unroll
    for (int r = 0; r < 4; r++) {
        const int t = t0 + lg * 4 + r;
        const float g0 = gate[t * 3 + 0];
#pragma unroll
        for (int nj = 0; nj < 8; nj++)
            obuf[(size_t)t * (H_ * D_) + h * D_ + nj * 16 + lc] = g0 * acc[nj][r];
    }
}

// ---------------------------------------------------------------------------
// top-k block selection -> bitmask
// ---------------------------------------------------------------------------
__global__ __launch_bounds__(256) void topk_k(const float* __restrict__ scg,
                                              unsigned int* __restrict__ amask) {
    const int t = blockIdx.x * 256 + threadIdx.x;
    if (t >= T_) return;
    float sc[NS_];
#pragma unroll
    for (int j = 0; j < NS_; j++)
        sc[j] = scg[((size_t)0 * T_ + t) * NS_ + j] + scg[((size_t)1 * T_ + t) * NS_ + j] +
                scg[((size_t)2 * T_ + t) * NS_ + j] + scg[((size_t)3 * T_ + t) * NS_ + j];
    const int cur = t >> 6;
    unsigned int chosen = 0;
    for (int it = 0; it < TOPK_ - 3; it++) {
        float best = 0.f;
        int bj = -1;
        for (int j = 0; j < NS_; j++) {
            if ((chosen >> j) & 1u) continue;
            const float v = (j >= cur) ? -INFINITY : sc[j];
            if (bj < 0 || v > best) { best = v; bj = j; }
        }
        chosen |= 1u << bj;
    }
    int f1 = cur - 2; if (f1 < 0) f1 = 0;
    int f2 = cur - 1; if (f2 < 0) f2 = 0;
    chosen |= 1u | (1u << f1) | (1u << f2) | (1u << cur);
    amask[t] = chosen;
}

// ---------------------------------------------------------------------------
// Online-softmax step for one masked stream (wave-private P buffer)
// ---------------------------------------------------------------------------
DEV void stream_step(const float lgv[4][4], float m[4], float lsum[4], f32x4 acc[8],
                     unsigned short* PsW, const unsigned short* VtS, int l) {
    const int lc = l & 15, lg = l >> 4;
    float mn[4], scf[4], rs[4];
    bool need = false;
#pragma unroll
    for (int r = 0; r < 4; r++) {
        float rm = fmaxf(fmaxf(lgv[0][r], lgv[1][r]), fmaxf(lgv[2][r], lgv[3][r]));
#pragma unroll
        for (int o = 1; o < 16; o <<= 1) rm = fmaxf(rm, __shfl_xor(rm, o));
        mn[r] = fmaxf(m[r], rm);
        scf[r] = __expf(m[r] - mn[r]);
        need |= (mn[r] > m[r]);
        m[r] = mn[r];
        rs[r] = 0.f;
    }
    float pv[4][4];
#pragma unroll
    for (int kt = 0; kt < 4; kt++)
#pragma unroll
        for (int r = 0; r < 4; r++) {
            const float p = (lgv[kt][r] <= -1e29f) ? 0.f : __expf(lgv[kt][r] - mn[r]);
            pv[kt][r] = p;
            rs[r] += p;
        }
#pragma unroll
    for (int r = 0; r < 4; r++) {
#pragma unroll
        for (int o = 1; o < 16; o <<= 1) rs[r] += __shfl_xor(rs[r], o);
        lsum[r] = lsum[r] * scf[r] + rs[r];
    }
    if (__any(need)) {
#pragma unroll
        for (int j = 0; j < 8; j++)
#pragma unroll
            for (int r = 0; r < 4; r++) acc[j][r] *= scf[r];
    }
#pragma unroll
    for (int kt = 0; kt < 4; kt++)
#pragma unroll
        for (int r = 0; r < 4; r++) {
            const int row = lg * 4 + r;
            const int col = kt * 16 + lc;
            PsW[row * 64 + (col ^ ((row & 7) << 3))] = f2b(pv[kt][r]);
        }
    __builtin_amdgcn_s_setprio(1);
#pragma unroll
    for (int ks2 = 0; ks2 < 2; ks2++) {
        short8 af = *(const short8*)&PsW[lc * 64 + ((ks2 * 32 + lg * 8) ^ ((lc & 7) << 3))];
#pragma unroll
        for (int j = 0; j < 8; j++) {
            const int dd = j * 16 + lc;
            const int sdd = (((dd & 7) ^ ((dd >> 3) & 7)) << 3);
            short8 bf = *(const short8*)&VtS[dd * 64 + ((ks2 * 32 + lg * 8) ^ sdd)];
            acc[j] = __builtin_amdgcn_mfma_f32_16x16x32_bf16(af, bf, acc[j], 0, 0, 0);
        }
    }
    __builtin_amdgcn_s_setprio(0);
}

// ---------------------------------------------------------------------------
// SLC+SWA partial kernel (split-K, 2 segments, rank-interleaved jb list).
// Block = (qb, h, seg), heaviest-first dispatch. K direct from L2,
// V^T double-buffered in LDS. Writes (m,l) f32 + acc bf16 partials.
// ---------------------------------------------------------------------------
__global__ __launch_bounds__(256) void slc_swa_pt(const unsigned short* __restrict__ qkvb,
                                                  const unsigned int* __restrict__ amask,
                                                  float* __restrict__ mlp,
                                                  unsigned short* __restrict__ accp) {
    const int bid = blockIdx.x;               // 1024 blocks
    const int qb = 31 - (bid >> 5);
    const int hs = bid & 31;
    const int h = hs >> 1, seg = hs & 1;
    const int t0 = qb * 64;
    const int cur = qb;
    const int kv = h >> 2;
    const int tid = threadIdx.x;
    const int w = tid >> 6, l = tid & 63;
    const int lc = l & 15, lg = l >> 4;

    __shared__ __align__(16) unsigned short Vt[2][128 * 64];
    __shared__ __align__(16) unsigned short Ps[4][16 * 64];
    __shared__ unsigned int am[64];
    __shared__ unsigned char lists[32];
    __shared__ int cnt_s;

    if (tid < 64) am[tid] = amask[t0 + tid];
    __syncthreads();
    if (tid == 0) {
        unsigned int u = 0;
        for (int i = 0; i < 64; i++) u |= am[i];
        const unsigned int curm = (cur >= 31) ? 0xFFFFFFFFu : ((1u << (cur + 1)) - 1u);
        int sl = qb - 8; if (sl < 0) sl = 0;
        const unsigned int swab = curm & ~((1u << sl) - 1u);
        const unsigned int act = (u & curm) | swab;
        int n = 0, rank = 0;
        for (int jb = 0; jb <= cur; jb++)
            if ((act >> jb) & 1u) {
                if ((rank & 1) == seg) lists[n++] = (unsigned char)jb;
                rank++;
            }
        cnt_s = n;
    }
    __syncthreads();
    const int cnt = cnt_s;

    // per-wave unions / bounds
    unsigned int uni16 = 0;
#pragma unroll
    for (int i = 0; i < 16; i++) uni16 |= am[w * 16 + i];
    const int tmin_w = t0 + w * 16;

    int tq[4];
    unsigned int amr[4];
#pragma unroll
    for (int r = 0; r < 4; r++) {
        const int rl = w * 16 + lg * 4 + r;
        tq[r] = t0 + rl;
        amr[r] = am[rl];
    }

    short8 aq[4];
    {
        const unsigned short* qp = qkvb + (size_t)(t0 + w * 16 + lc) * QKV_N + h * D_ + lg * 8;
#pragma unroll
        for (int ks = 0; ks < 4; ks++) aq[ks] = *(const short8*)(qp + ks * 32);
    }

    f32x4 acc_s[8] = {};
    f32x4 acc_w[8] = {};
    float m_s[4], l_s[4], m_w[4], l_w[4];
#pragma unroll
    for (int r = 0; r < 4; r++) { m_s[r] = -1e30f; l_s[r] = 0.f; m_w[r] = -1e30f; l_w[r] = 0.f; }

    const int kcol0 = H_ * D_ + kv * D_;
    const int vcol0 = H_ * D_ + KVH * D_ + kv * D_;
    const int d0 = (tid & 15) * 8;
    const int kk = tid >> 4;

    if (cnt > 0) {
        // prologue: stage V(list[0]) into buf 0
        {
            const int jb0 = lists[0];
#pragma unroll
            for (int mIt = 0; mIt < 4; mIt++) {
                const int kk2 = kk + mIt * 16;
                short8 vvals = *(const short8*)(qkvb + (size_t)(jb0 * 64 + kk2) * QKV_N + vcol0 + d0);
#pragma unroll
                for (int j = 0; j < 8; j++) {
                    const int dd = d0 + j;
                    const int sdd = (((dd & 7) ^ ((dd >> 3) & 7)) << 3);
                    Vt[0][dd * 64 + (kk2 ^ sdd)] = (unsigned short)vvals[j];
                }
            }
        }
        int buf = 0;
        for (int i = 0; i < cnt; i++) {
            const int jb = lists[i];
            __syncthreads();   // V(jb) ready in buf; prev compute done -> buf^1 free
            if (i + 1 < cnt) {
                const int jn = lists[i + 1];
#pragma unroll
                for (int mIt = 0; mIt < 4; mIt++) {
                    const int kk2 = kk + mIt * 16;
                    short8 vvals = *(const short8*)(qkvb + (size_t)(jn * 64 + kk2) * QKV_N + vcol0 + d0);
#pragma unroll
                    for (int j = 0; j < 8; j++) {
                        const int dd = d0 + j;
                        const int sdd = (((dd & 7) ^ ((dd >> 3) & 7)) << 3);
                        Vt[buf ^ 1][dd * 64 + (kk2 ^ sdd)] = (unsigned short)vvals[j];
                    }
                }
            }
            const bool slc_w = (uni16 >> jb) & 1u;
            const bool swa_w = (jb * 64 + 63) > (tmin_w - WIN_);
            if (slc_w || swa_w) {
                // K B-frags direct from L2
                f32x4 sfr[4] = {};
                __builtin_amdgcn_s_setprio(1);
#pragma unroll
                for (int kt = 0; kt < 4; kt++) {
                    const unsigned short* kp =
                        qkvb + (size_t)(jb * 64 + kt * 16 + lc) * QKV_N + kcol0 + lg * 8;
#pragma unroll
                    for (int ks = 0; ks < 4; ks++) {
                        short8 bf = *(const short8*)(kp + ks * 32);
                        sfr[kt] = __builtin_amdgcn_mfma_f32_16x16x32_bf16(aq[ks], bf, sfr[kt], 0, 0, 0);
                    }
                }
                __builtin_amdgcn_s_setprio(0);
                float base[4][4];
#pragma unroll
                for (int kt = 0; kt < 4; kt++)
#pragma unroll
                    for (int r = 0; r < 4; r++) base[kt][r] = sfr[kt][r] * SCALE_;

                if (slc_w) {
                    float lgv[4][4];
#pragma unroll
                    for (int kt = 0; kt < 4; kt++) {
                        const int kpos = jb * 64 + kt * 16 + lc;
#pragma unroll
                        for (int r = 0; r < 4; r++) {
                            const bool ok = (kpos <= tq[r]) && ((amr[r] >> jb) & 1u);
                            lgv[kt][r] = ok ? base[kt][r] : -1e30f;
                        }
                    }
                    stream_step(lgv, m_s, l_s, acc_s, Ps[w], Vt[buf], l);
                }
                if (swa_w) {
                    float lgv[4][4];
#pragma unroll
                    for (int kt = 0; kt < 4; kt++) {
                        const int kpos = jb * 64 + kt * 16 + lc;
#pragma unroll
                        for (int r = 0; r < 4; r++) {
                            const bool ok = (kpos <= tq[r]) && (kpos > tq[r] - WIN_);
                            lgv[kt][r] = ok ? base[kt][r] : -1e30f;
                        }
                    }
                    stream_step(lgv, m_w, l_w, acc_w, Ps[w], Vt[buf], l);
                }
            }
            buf ^= 1;
        }
    }

    // epilogue: write partials
    const size_t base2 = (size_t)(qb * 16 + h) * 2 + seg;
    if (lc == 0) {
#pragma unroll
        for (int r = 0; r < 4; r++) {
            const int row = w * 16 + lg * 4 + r;
            float4v v;
            v[0] = m_s[r]; v[1] = l_s[r]; v[2] = m_w[r]; v[3] = l_w[r];
            *(float4v*)&mlp[(base2 * 64 + row) * 4] = v;
        }
    }
#pragma unroll
    for (int st = 0; st < 2; st++) {
        const f32x4* A = st ? acc_w : acc_s;
#pragma unroll
        for (int nj = 0; nj < 8; nj++)
#pragma unroll
            for (int r = 0; r < 4; r++) {
                const int row = w * 16 + lg * 4 + r;
                accp[((base2 * 2 + st) * 64 + row) * 128 + nj * 16 + lc] = f2b(A[nj][r]);
            }
    }
}

// ---------------------------------------------------------------------------
// Combine segments + gating + obuf add -> bf16 o
// ---------------------------------------------------------------------------
__global__ __launch_bounds__(256) void slc_comb(const float* __restrict__ obuf,
                                                const float* __restrict__ mlp,
                                                const unsigned short* __restrict__ accp,
                                                const float* __restrict__ gate,
                                                const float* __restrict__ sinks,
                                                unsigned short* __restrict__ obufb) {
    const int t = blockIdx.x;
    const int qb = t >> 6, row = t & 63;
    const int tid = threadIdx.x;
    const int d = tid & 127, half = tid >> 7;
    const float g1 = gate[t * 3 + 1], g2 = gate[t * 3 + 2];
#pragma unroll
    for (int hh = 0; hh < 8; hh++) {
        const int h = half * 8 + hh;
        const size_t base2 = (size_t)(qb * 16 + h) * 2;
        const float4v ml0 = *(const float4v*)&mlp[((base2 + 0) * 64 + row) * 4];
        const float4v ml1 = *(const float4v*)&mlp[((base2 + 1) * 64 + row) * 4];
        // slc merge
        const float Ms = fmaxf(ml0[0], ml1[0]);
        const float e0 = __expf(ml0[0] - Ms), e1 = __expf(ml1[0] - Ms);
        const float ls = ml0[1] * e0 + ml1[1] * e1;
        const float a0 = b2f(accp[(((base2 + 0) * 2 + 0) * 64 + row) * 128 + d]);
        const float a1 = b2f(accp[(((base2 + 1) * 2 + 0) * 64 + row) * 128 + d]);
        const float os = (a0 * e0 + a1 * e1) / ls;
        // swa merge (with sink)
        const float snk = sinks[h];
        const float Mw = fmaxf(fmaxf(ml0[2], ml1[2]), snk);
        const float w0 = __expf(ml0[2] - Mw), w1 = __expf(ml1[2] - Mw);
        const float den = ml0[3] * w0 + ml1[3] * w1 + __expf(snk - Mw);
        const float b0 = b2f(accp[(((base2 + 0) * 2 + 1) * 64 + row) * 128 + d]);
        const float b1 = b2f(accp[(((base2 + 1) * 2 + 1) * 64 + row) * 128 + d]);
        const float ow = (b0 * w0 + b1 * w1) / den;
        const size_t idx = (size_t)t * (H_ * D_) + h * D_ + d;
        obufb[idx] = f2b(obuf[idx] + g1 * os + g2 * ow);
    }
}

// ---------------------------------------------------------------------------
// Fallback (round-3 proven): monolithic SLC+SWA, accumulates into obuf f32
// ---------------------------------------------------------------------------
__global__ __launch_bounds__(256) void slc_swa(const unsigned short* __restrict__ qkvb,
                                               const unsigned int* __restrict__ amask,
                                               const float* __restrict__ gate,
                                               const float* __restrict__ sinks,
                                               float* __restrict__ obuf) {
    const int bid = blockIdx.x;
    const int h = bid & 15;
    const int xx = bid >> 4;
    const int qb = (xx & 1) ? (xx >> 1) : (31 - (xx >> 1));
    const int t0 = qb * 64;
    const int cur = qb;
    const int kv = h >> 2;
    const int tid = threadIdx.x;
    const int w = tid >> 6, l = tid & 63;
    const int lc = l & 15, lg = l >> 4;

    __shared__ __align__(16) unsigned short Ks[64 * 128];
    __shared__ __align__(16) unsigned short Vt[128 * 64];
    __shared__ __align__(16) unsigned short Ps[4][16 * 64];
    __shared__ unsigned int am[64];
    __shared__ unsigned int uni_s;

    if (tid < 64) am[tid] = amask[t0 + tid];
    __syncthreads();
    if (tid == 0) {
        unsigned int u = 0;
        for (int i = 0; i < 64; i++) u |= am[i];
        uni_s = u;
    }
    __syncthreads();
    const unsigned int uni = uni_s;

    int tq[4];
    unsigned int amr[4];
#pragma unroll
    for (int r = 0; r < 4; r++) {
        const int rl = w * 16 + lg * 4 + r;
        tq[r] = t0 + rl;
        amr[r] = am[rl];
    }

    short8 aq[4];
    {
        const unsigned short* qp = qkvb + (size_t)(t0 + w * 16 + lc) * QKV_N + h * D_ + lg * 8;
#pragma unroll
        for (int ks = 0; ks < 4; ks++) aq[ks] = *(const short8*)(qp + ks * 32);
    }

    f32x4 acc_s[8] = {};
    f32x4 acc_w[8] = {};
    float m_s[4], l_s[4], m_w[4], l_w[4];
#pragma unroll
    for (int r = 0; r < 4; r++) { m_s[r] = -1e30f; l_s[r] = 0.f; m_w[r] = -1e30f; l_w[r] = 0.f; }

    const int kcol0 = H_ * D_ + kv * D_;
    const int vcol0 = H_ * D_ + KVH * D_ + kv * D_;

    for (int jb = 0; jb <= cur; jb++) {
        const bool slc_on = (uni >> jb) & 1u;
        const bool swa_on = (jb * 64 + 63) > (t0 - WIN_);
        if (!slc_on && !swa_on) continue;
        __syncthreads();
        {
            const int d0 = (tid & 15) * 8;
            const int kk = tid >> 4;
#pragma unroll
            for (int mIt = 0; mIt < 4; mIt++) {
                const int kk2 = kk + mIt * 16;
                const size_t row = (size_t)(jb * 64 + kk2) * QKV_N;
                short8 kvals = *(const short8*)(qkvb + row + kcol0 + d0);
                *(short8*)&Ks[kk2 * 128 + (d0 ^ ((kk2 & 7) << 3))] = kvals;
                short8 vvals = *(const short8*)(qkvb + row + vcol0 + d0);
#pragma unroll
                for (int j = 0; j < 8; j++) {
                    const int dd = d0 + j;
                    const int sdd = (((dd & 7) ^ ((dd >> 3) & 7)) << 3);
                    Vt[dd * 64 + (kk2 ^ sdd)] = (unsigned short)vvals[j];
                }
            }
        }
        __syncthreads();
        f32x4 sfr[4] = {};
#pragma unroll
        for (int kt = 0; kt < 4; kt++) {
            const int key = kt * 16 + lc;
#pragma unroll
            for (int ks = 0; ks < 4; ks++) {
                short8 bf = *(const short8*)&Ks[key * 128 + ((ks * 32 + lg * 8) ^ ((key & 7) << 3))];
                sfr[kt] = __builtin_amdgcn_mfma_f32_16x16x32_bf16(aq[ks], bf, sfr[kt], 0, 0, 0);
            }
        }
        float base[4][4];
#pragma unroll
        for (int kt = 0; kt < 4; kt++)
#pragma unroll
            for (int r = 0; r < 4; r++) base[kt][r] = sfr[kt][r] * SCALE_;

        if (slc_on) {
            float lgv[4][4];
#pragma unroll
            for (int kt = 0; kt < 4; kt++) {
                const int kpos = jb * 64 + kt * 16 + lc;
#pragma unroll
                for (int r = 0; r < 4; r++) {
                    const bool ok = (kpos <= tq[r]) && ((amr[r] >> jb) & 1u);
                    lgv[kt][r] = ok ? base[kt][r] : -1e30f;
                }
            }
            stream_step(lgv, m_s, l_s, acc_s, Ps[w], Vt, l);
        }
        if (swa_on) {
            float lgv[4][4];
#pragma unroll
            for (int kt = 0; kt < 4; kt++) {
                const int kpos = jb * 64 + kt * 16 + lc;
#pragma unroll
                for (int r = 0; r < 4; r++) {
                    const bool ok = (kpos <= tq[r]) && (kpos > tq[r] - WIN_);
                    lgv[kt][r] = ok ? base[kt][r] : -1e30f;
                }
            }
            stream_step(lgv, m_w, l_w, acc_w, Ps[w], Vt, l);
        }
    }

    const float snk = sinks[h];
#pragma unroll
    for (int r = 0; r < 4; r++) {
        const int t = tq[r];
        const float g1 = gate[t * 3 + 1], g2 = gate[t * 3 + 2];
        const float invs = 1.f / l_s[r];
        const float Mx = fmaxf(m_w[r], snk);
        const float ew = __expf(m_w[r] - Mx);
        const float fw = ew / (l_w[r] * ew + __expf(snk - Mx));
#pragma unroll
        for (int j = 0; j < 8; j++) {
            const int dd = j * 16 + lc;
            const size_t idx = (size_t)t * (H_ * D_) + h * D_ + dd;
            obuf[idx] += g1 * acc_s[j][r] * invs + g2 * acc_w[j][r] * fw;
        }
    }
}

// ---------------------------------------------------------------------------
extern "C" void kernel_launch(void* const* d_in, const int* in_sizes, int n_in,
                              void* d_out, int out_size, void* d_ws, size_t ws_size,
                              hipStream_t stream) {
    const float* x = (const float*)d_in[0];
    const float* W_qkv = (const float*)d_in[1];
    const float* b_qkv = (const float*)d_in[2];
    const float* W_out = (const float*)d_in[3];
    const float* b_out = (const float*)d_in[4];
    const float* sinks = (const float*)d_in[5];
    const float* cmp_pos = (const float*)d_in[6];
    const float* W_c1 = (const float*)d_in[7];
    const float* b_c1 = (const float*)d_in[8];
    const float* W_c2 = (const float*)d_in[9];
    const float* b_c2 = (const float*)d_in[10];
    const float* W_g1 = (const float*)d_in[11];
    const float* b_g1 = (const float*)d_in[12];
    const float* W_g2 = (const float*)d_in[13];
    const float* b_g2 = (const float*)d_in[14];

    char* ws = (char*)d_ws;
    unsigned short* qkvb = (unsigned short*)(ws + 0);          // 12,582,912
    unsigned short* obufb_fb = (unsigned short*)(ws + 0);      // fallback: reuses qkvb
    char* A0 = ws + 12582912;                                  // 16,777,216 region
    unsigned short* Wqkv_b = (unsigned short*)(A0);
    float* hgate = (float*)(A0);
    unsigned short* Wg1_b = (unsigned short*)(A0 + 12582912);
    unsigned short* blkb = (unsigned short*)(A0);
    float* obuf = (float*)(A0);
    char* B0 = ws + 29360128;                                  // 8,388,608 region
    unsigned short* x_b = (unsigned short*)(B0);
    unsigned short* Wc1_b = (unsigned short*)(B0);
    unsigned short* Wc2_b = (unsigned short*)(B0 + 2097152);
    unsigned short* hc_b = (unsigned short*)(B0 + 2162688);
    unsigned short* hcmpb = (unsigned short*)(B0 + 3211264);
    unsigned short* obufb_sp = (unsigned short*)(B0);          // split: o bf16 (after cmp path dead)
    unsigned short* Wout_b_fb = (unsigned short*)(B0);         // fallback Wout
    float* gateb = (float*)(ws + 37748736);                    // 24,576
    unsigned int* amaskb = (unsigned int*)(ws + 37773312);     // 8,192
    float* scg = (float*)(ws + 37781504);                      // 1,048,576 -> end 38,830,080
    float* mlp = (float*)(ws + 38830080);                      // 1,048,576 -> 39,878,656
    unsigned short* accp = (unsigned short*)(ws + 39878656);   // 33,554,432 -> 73,433,088
    unsigned short* Wout_b_sp = (unsigned short*)(ws + 38830080); // split: after comb, over mlp/accp
    float* outf = (float*)d_out;

    const bool SPLIT = (ws_size >= 73433088ull);

    // 0) bf16 conversions for the early GEMMs
    cvt_f2b<<<dim3(4096), 256, 0, stream>>>(x, x_b, T_ * DIM_);
    cvt_f2b<<<dim3(6144), 256, 0, stream>>>(W_qkv, Wqkv_b, QKV_N * DIM_);
    cvt_f2b<<<dim3(1024), 256, 0, stream>>>(W_g1, Wg1_b, GATE_HID_ * DIM_);
    // 1) qkv (bf16 out)
    gemm_f<0, false, true><<<dim3(QKV_N / 128, T_ / 128), 256, 0, stream>>>(
        x_b, Wqkv_b, b_qkv, nullptr, qkvb, T_, QKV_N, DIM_);
    // 2) gate hidden
    gemm_f<1, true, false><<<dim3(GATE_HID_ / 128, T_ / 128), 256, 0, stream>>>(
        x_b, Wg1_b, b_g1, hgate, nullptr, T_, GATE_HID_, DIM_);
    // 3) gates
    gate2_k<<<dim3(1536), 256, 0, stream>>>(hgate, W_g2, b_g2, gateb);
    // 4) compression weights to bf16
    cvt_f2b<<<dim3(1024), 256, 0, stream>>>(W_c1, Wc1_b, 256 * LL * D_);
    cvt_f2b<<<dim3(32), 256, 0, stream>>>(W_c2, Wc2_b, D_ * 256);
    // 5) compression inputs
    blk_build<<<dim3(2048), 256, 0, stream>>>(qkvb, cmp_pos, blkb);
    // 6) compression MLP
    gemm_f<1, false, true><<<dim3(2, 16), 256, 0, stream>>>(
        blkb, Wc1_b, b_c1, nullptr, hc_b, 2048, 256, LL * D_);
    gemm_f<0, false, true><<<dim3(1, 16), 256, 0, stream>>>(
        hc_b, Wc2_b, b_c2, nullptr, hcmpb, 2048, D_, 256);
    // 7) CMP attention + block-score slices; obuf = g0*o_cmp
    cmp_attn2<<<dim3(512), 256, 0, stream>>>(qkvb, hcmpb, hcmpb + 1024 * D_, gateb, obuf, scg);
    // 8) top-k -> mask
    topk_k<<<dim3(T_ / 256), 256, 0, stream>>>(scg, amaskb);

    if (SPLIT) {
        // 9) split SLC+SWA partials + combine (fuses gating + bf16 cvt)
        slc_swa_pt<<<dim3(1024), 256, 0, stream>>>(qkvb, amaskb, mlp, accp);
        slc_comb<<<dim3(T_), 256, 0, stream>>>(obuf, mlp, accp, gateb, sinks, obufb_sp);
        // 10) out = o @ W_out^T + b_out
        cvt_f2b<<<dim3(4096), 256, 0, stream>>>(W_out, Wout_b_sp, DIM_ * H_ * D_);
        gemm_f<0, true, false><<<dim3(DIM_ / 128, T_ / 128), 256, 0, stream>>>(
            obufb_sp, Wout_b_sp, b_out, outf, nullptr, T_, DIM_, H_ * D_);
    } else {
        // fallback: round-3 proven path
        cvt_f2b<<<dim3(4096), 256, 0, stream>>>(W_out, Wout_b_fb, DIM_ * H_ * D_);
        slc_swa<<<dim3(512), 256, 0, stream>>>(qkvb, amaskb, gateb, sinks, obuf);
        cvt_f2b<<<dim3(4096), 256, 0, stream>>>(obuf, obufb_fb, T_ * H_ * D_);
        gemm_f<0, true, false><<<dim3(DIM_ / 128, T_ / 128), 256, 0, stream>>>(
            obufb_fb, Wout_b_fb, b_out, outf, nullptr, T_, DIM_, H_ * D_);
    }
}